// Round 7
// baseline (448.041 us; speedup 1.0000x reference)
//
#include <hip/hip_runtime.h>
#include <type_traits>

#define NODE 400
#define POP 3
#define TRS 40
#define STEPS 10
#define DMAX 500
#define OUT 64
#define DT 0.1f
#define JPL 7           // ceil(NODE/64) j-indices per lane
#define WSTR 512        // per-stream W bin stride (delta in [0,511])

__device__ __forceinline__ float relu_(float x) { return x > 0.f ? x : 0.f; }
__device__ __forceinline__ float rcp_(float x) { return __builtin_amdgcn_rcpf(x); }
__device__ __forceinline__ float rlane_(float v, int l) {
  return __builtin_bit_cast(float, __builtin_amdgcn_readlane(__builtin_bit_cast(int, v), l));
}
// broadcast lane 0 to all lanes, VGPR result (slow-path harvest)
__device__ __forceinline__ float bperm0_(float v) {
  return __builtin_bit_cast(float,
      __builtin_amdgcn_ds_bpermute(0, __builtin_bit_cast(int, v)));
}
// ds_swizzle BitMode: src_lane = ((lane & and) | or) ^ xor within each
// 32-lane group. OFF = (xor<<10)|(or<<5)|and. and=0,xor=0 -> every lane reads
// lane 'or' of its OWN 32-group (half-local broadcast). Verified r4-r6.
template <int OFF>
__device__ __forceinline__ float swz_(float v) {
  return __builtin_bit_cast(float,
      __builtin_amdgcn_ds_swizzle(__builtin_bit_cast(int, v), OFF));
}
// pin a value into a VGPR
#define PIN_V(x) asm volatile("" : "+v"(x))

// ---- DPP helpers
template <int CTRL>
__device__ __forceinline__ float dpp_mov(float x) {
  int r = __builtin_amdgcn_update_dpp(0, __builtin_bit_cast(int, x), CTRL,
                                      0xf, 0xf, true);
  return __builtin_bit_cast(float, r);
}
template <int CTRL>
__device__ __forceinline__ int dpp_movi(int x) {
  return __builtin_amdgcn_update_dpp(0, x, CTRL, 0xf, 0xf, true);
}
// wave rotate: dst[L] = src[(L+1) & 63]  (wave_rol:1 = 0x134, verified r1-r6)
__device__ __forceinline__ float wrol1(float x) { return dpp_mov<0x134>(x); }

__device__ __forceinline__ void wave_reduce3(float& a, float& b, float& c) {
  a += dpp_mov<0x111>(a); b += dpp_mov<0x111>(b); c += dpp_mov<0x111>(c);
  a += dpp_mov<0x112>(a); b += dpp_mov<0x112>(b); c += dpp_mov<0x112>(c);
  a += dpp_mov<0x114>(a); b += dpp_mov<0x114>(b); c += dpp_mov<0x114>(c);
  a += dpp_mov<0x118>(a); b += dpp_mov<0x118>(b); c += dpp_mov<0x118>(c);
  a += dpp_mov<0x142>(a); b += dpp_mov<0x142>(b); c += dpp_mov<0x142>(c);
  a += dpp_mov<0x143>(a); b += dpp_mov<0x143>(b); c += dpp_mov<0x143>(c);
  a = rlane_(a, 63); b = rlane_(b, 63); c = rlane_(c, 63);
}

__device__ __forceinline__ float wave_reduce1(float a) {
  a += dpp_mov<0x111>(a); a += dpp_mov<0x112>(a); a += dpp_mov<0x114>(a);
  a += dpp_mov<0x118>(a); a += dpp_mov<0x142>(a); a += dpp_mov<0x143>(a);
  return rlane_(a, 63);
}

__device__ __forceinline__ int wave_max_int(int x) {
  x = max(x, dpp_movi<0x111>(x));
  x = max(x, dpp_movi<0x112>(x));
  x = max(x, dpp_movi<0x114>(x));
  x = max(x, dpp_movi<0x118>(x));
  x = max(x, dpp_movi<0x142>(x));
  x = max(x, dpp_movi<0x143>(x));
  return __builtin_amdgcn_readlane(x, 63);
}

// ---------------------------------------------------------------------------
// Kernel A: Frobenius sum-of-squares partials (64 blocks, no atomics).
// ---------------------------------------------------------------------------
__global__ __launch_bounds__(256) void ssq_kernel(
    const float* __restrict__ wbb, const float* __restrict__ wff,
    const float* __restrict__ wll, const float* __restrict__ sc,
    float* __restrict__ part) {
  float eb = 0.f, ef = 0.f, el = 0.f;
  for (int idx = blockIdx.x * 256 + threadIdx.x; idx < NODE * NODE;
       idx += 64 * 256) {
    int i = idx / NODE, j = idx - i * NODE;
    int ji = j * NODE + i;
    float scij = sc[idx];
    float b = expf(wbb[idx]) * scij;
    float f = expf(wff[idx]) * scij;
    float l = 0.5f * (expf(wll[idx]) * scij + expf(wll[ji]) * sc[ji]);
    eb = fmaf(b, b, eb); ef = fmaf(f, f, ef); el = fmaf(l, l, el);
  }
  wave_reduce3(eb, ef, el);
  __shared__ float red[3][4];
  int lane = threadIdx.x & 63, wv = threadIdx.x >> 6;
  if (lane == 0) { red[0][wv] = eb; red[1][wv] = ef; red[2][wv] = el; }
  __syncthreads();
  if (threadIdx.x == 0) {
    part[blockIdx.x]       = red[0][0] + red[0][1] + red[0][2] + red[0][3];
    part[64 + blockIdx.x]  = red[1][0] + red[1][1] + red[1][2] + red[1][3];
    part[128 + blockIdx.x] = red[2][0] + red[2][1] + red[2][2] + red[2][3];
  }
}

// ---------------------------------------------------------------------------
// Kernel B fast path (r7): POP-SPLIT + FULLY-DEFERRED schedule.
// Two nodes per block as 32-lane halves; lane ownes pop (hlane%3), truth on
// hlanes 0/1/2 (+32). All cross-lane values (sigmaE/I/P, t2, t3) are produced
// in body t and consumed in body t+1 -> latency fully hidden. Ring uses the
// DEFERRED-SCATTER form: rotation at body t merges the scatter of s(t-1)
// (weights shifted one slot, Wsh[r]=W[slot+1]); harvest carries the W0
// correction a(t) = Q[0] + W0*s(t-1). Semantically exact (E(t) needs exactly
// sigma(t-1)). Q0 = P0 - W[slot]*hE[0].
// ---------------------------------------------------------------------------
__global__ __launch_bounds__(128) void sim_kernel(
    const float* __restrict__ external, const float* __restrict__ hx,
    const float* __restrict__ hE, const float* __restrict__ sc,
    const float* __restrict__ dist, const float* __restrict__ wbb,
    const float* __restrict__ wff, const float* __restrict__ wll,
    const float* __restrict__ theta, const float* __restrict__ part,
    float* __restrict__ vsnap) {
  const int wv = threadIdx.x >> 6;
  const int lane = threadIdx.x & 63;
  const int node = blockIdx.x * 2 + wv;   // this wave's setup node

  __shared__ float Wall[2][3 * WSTR];   // per node: Wl | Wf | Wb (pre-scaled)
  __shared__ float hE_lds[2][DMAX];
  __shared__ float u_lds[2][STEPS * TRS];
  __shared__ float sc_c[2][3];          // rl, rf, rb (scaled row sums)
  __shared__ int   sc_md[2];            // per-node maxd

  // --- global norm sums from ssq partials (one DPP reduce) ---
  float sb = part[lane], sf = part[64 + lane], sl = part[128 + lane];
  wave_reduce3(sb, sf, sl);
  const float inv_nb = 1.f / sqrtf(sb);
  const float inv_nf = 1.f / sqrtf(sf);
  const float inv_nl = 1.f / sqrtf(sl);

  // --- parameters ---
  const float VL = relu_(theta[0]), VI = relu_(theta[1]);
  const float VE = relu_(theta[2]), VNMDA = relu_(theta[3]);
  const float alpha_mg = relu_(theta[4]), VR = relu_(theta[5]);
  const float pi_sigma = relu_(theta[6]);
  const float gLp = relu_(theta[7]), Cc = relu_(theta[8]), kappa = relu_(theta[9]);
  const float g_gE = relu_(theta[10]), g_gE_sc = relu_(theta[11]);
  const float g_gI = relu_(theta[12]), g_gI_sc = relu_(theta[13]);
  const float g_gN = relu_(theta[14]), g_gN_sc = relu_(theta[15]);
  const float g_k = relu_(theta[16]);
  const float mu = 0.1f + relu_(theta[20]);
  const float uk = relu_(theta[21]) * theta[23];
  const float g_l = relu_(theta[24]), g_f = relu_(theta[25]), g_b = relu_(theta[26]);
  const float DTC = DT / Cc;
  const float dk = DT * kappa;
  const float nps = -pi_sigma, psVR = pi_sigma * VR;
  const float nam = -alpha_mg;

  const float dk1  = 1.f - dk;
  const float cA   = dk * g_l;     // folded into Wl bins
  const float cF   = dk * g_f;     // folded into Wf bins
  const float cB   = dk * g_b;     // folded into Wb bins
  const float cE0s = dk * g_gE;
  const float cE1e = dk * g_gE_sc;
  const float cE2e = dk * g_k;
  const float cI0  = dk * g_gI;
  const float cI1  = dk * g_gI_sc;
  const float cN0s = dk * g_gN;
  const float cN1  = dk * g_gN_sc;
  const float cN2  = dk * g_gN;
  const float gLVL = gLp * VL;
  const float L2E = 1.44269504088896f;
  const float npsL2 = nps * L2E;
  const float namL2 = nam * L2E;

  // --- stage LDS (wave w handles node w's slabs) ---
  for (int k = lane; k < 3 * WSTR; k += 64) Wall[wv][k] = 0.f;
  for (int d = lane; d < DMAX; d += 64) hE_lds[wv][d] = hE[node * DMAX + d];
  const float ukdk = dk * uk;
  for (int t = lane; t < STEPS * TRS; t += 64)
    u_lds[wv][t] = ukdk * external[node * STEPS * TRS + t];

  // --- bin weights by delay (pre-scaled), row sums, max delay ---
  const float scl = inv_nl * cA, scf = inv_nf * cF, scb = inv_nb * cB;
  float rl = 0.f, rf = 0.f, rb = 0.f;
  int mymax = 0;
#pragma unroll
  for (int kj = 0; kj < JPL; ++kj) {
    int j = lane + kj * 64;
    if (j < NODE) {
      int ij = node * NODE + j;
      int ji = j * NODE + node;
      float scij = sc[ij];
      float vb = expf(wbb[ij]) * scij * scb;
      float vf = expf(wff[ij]) * scij * scf;
      float vl = 0.5f * (expf(wll[ij]) * scij + expf(wll[ji]) * sc[ji]) * scl;
      int dd = (int)(dist[ij] / mu);
      dd = min(max(dd, 0), DMAX - 1);
      atomicAdd(&Wall[wv][dd], vl);
      atomicAdd(&Wall[wv][WSTR + dd], vf);
      atomicAdd(&Wall[wv][2 * WSTR + dd], vb);
      rl += vl; rf += vf; rb += vb;
      mymax = max(mymax, dd);
    }
  }
  wave_reduce3(rl, rf, rb);
  const int maxd_w = wave_max_int(mymax);
  if (lane == 0) {
    sc_c[wv][0] = rl; sc_c[wv][1] = rf; sc_c[wv][2] = rb;
    sc_md[wv] = maxd_w;
  }
  __syncthreads();
  const int maxd = max(sc_md[0], sc_md[1]);

  if (maxd <= 126) {
    // ================= FAST PATH: wave 0 only, pop-split halves ============
    if (wv != 0) return;
    const int h = lane >> 5, hlane = lane & 31;
    const int nodeF = blockIdx.x * 2 + h;
    const int p3 = hlane % 3;             // owned population (truth: hlane<3)
    const bool isP1 = (p3 == 1), isP2 = (p3 == 2), isP0 = (p3 == 0);

    // per-half (per-node) scalars
    const float rlh = sc_c[h][0], rfh = sc_c[h][1], rbh = sc_c[h][2];
    const float cE0s2 = cE0s - rlh;
    const float cN0s2 = cN0s - rlh;
    const float cE1s = -rbh;
    const float cE2s = -rfh;
    // per-pop coefficient registers (VGPR; uniform dyn instruction stream)
    const float aE = isP1 ? cE1e : (isP2 ? cE2e : 0.f);
    const float bE = isP1 ? cE1s : (isP2 ? cE2s : cE0s2);
    const float uflag = isP1 ? 0.f : 1.f;
    const float cI = isP1 ? cI1 : cI0;
    const float pN = isP0 ? cN0s2 : 0.f;
    const float qN = isP1 ? cN1 : (isP2 ? cN2 : 0.f);
    float vngLVL = -gLVL;       PIN_V(vngLVL);
    float vpsVRL2 = psVR * L2E; PIN_V(vpsVRL2);

    // own-pop state (truth on hlanes 0/1/2; replicas drift harmlessly)
    const int hb = nodeF * POP * 4 + 4 * p3;
    float V = hx[hb + 0];
    float E = hx[hb + 1];
    float I = hx[hb + 2];
    float N = hx[hb + 3];

    const bool htop = (hlane == 31);
    constexpr int NR = 4;

    // shifted weights (deferred ring) + W0 bin values + hE[0]
    float Wshl[NR], Wshf[NR], Wshb[NR];
    const float W0l = Wall[h][0], W0f = Wall[h][WSTR], W0b = Wall[h][2 * WSTR];
    const float hE0 = hE_lds[h][0];
#pragma unroll
    for (int r = 0; r < NR; ++r) {
      int s = NR * hlane + r + 1;          // W[slot+1]; slot127->W[128]=0 ok
      Wshl[r] = Wall[h][s];
      Wshf[r] = Wall[h][WSTR + s];
      Wshb[r] = Wall[h][2 * WSTR + s];
    }

    // prologue: P0[slot] = sum_{d>=slot} W[d]*hE[d-slot]
    float Ql[NR], Qf[NR], Qb[NR], hbuf[NR];
#pragma unroll
    for (int r = 0; r < NR; ++r) { Ql[r] = 0.f; Qf[r] = 0.f; Qb[r] = 0.f; hbuf[r] = 0.f; }
    for (int d = 0; d <= maxd; ++d) {
      float wl_ = Wall[h][d], wf_ = Wall[h][WSTR + d], wb_ = Wall[h][2 * WSTR + d];
#pragma unroll
      for (int r = NR - 1; r > 0; --r) hbuf[r] = hbuf[r - 1];
      int idx = d - NR * hlane;
      bool ok = idx >= 0;
      float hv = hE_lds[h][ok ? idx : 0];
      hbuf[0] = ok ? hv : 0.f;
#pragma unroll
      for (int r = 0; r < NR; ++r) {
        Ql[r] = fmaf(wl_, hbuf[r], Ql[r]);
        Qf[r] = fmaf(wf_, hbuf[r], Qf[r]);
        Qb[r] = fmaf(wb_, hbuf[r], Qb[r]);
      }
    }
    // Q0 = P0 - W[slot]*hE0 (convert to deferred-scatter state)
#pragma unroll
    for (int r = 0; r < NR; ++r) {
      int s = NR * hlane + r;
      Ql[r] = fmaf(-Wall[h][s], hE0, Ql[r]);
      Qf[r] = fmaf(-Wall[h][WSTR + s], hE0, Qf[r]);
      Qb[r] = fmaf(-Wall[h][2 * WSTR + s], hE0, Qb[r]);
    }

    const float* uh = &u_lds[h][0];
    // deferred carries: broadcasts/locals produced at body t-1
    float bsE = 0.f, bsI = 0.f, bsP = hE0;   // sigma(t-1); s(-1)=hE[0]
    float bt2 = 0.f, bt3 = 0.f, t1c = 0.f, Uprev = 0.f;
    int uidx = 0, stc = 0, trc = 0;

    auto bodyfn = [&](auto doein) {
      // [1] own-pop sigma(t), m(t) from V(t)
      float sg = rcp_(1.f + __builtin_amdgcn_exp2f(fmaf(npsL2, V, vpsVRL2)));
      float mm = rcp_(fmaf(0.2f, __builtin_amdgcn_exp2f(namL2 * V), 1.f));
      // [2] harvest a(t) = Q[0] + W0*s(t-1)   (lane-0 correct; pre-ring)
      float t1n = fmaf(W0l, bsP, Ql[0]);
      float t2n = fmaf(W0f, bsP, Qf[0]);
      float t3n = fmaf(W0b, bsP, Qb[0]);
      // [3] issue next-body cross-lane traffic + U fetch (consumed body t+1)
      float nbsE = swz_<(0 << 5)>(sg);     // hlane0 = sigmaE
      float nbsI = swz_<(1 << 5)>(sg);     // hlane1 = sigmaI
      float nbsP = swz_<(2 << 5)>(sg);     // hlane2 = sigmaP
      float nbt2 = swz_<(0 << 5)>(t2n);    // from lane 0
      float nbt3 = swz_<(0 << 5)>(t3n);
      float Unew = uh[uidx];
      __builtin_amdgcn_sched_barrier(0);
      // [4] E/I/N <- step-t values using PREV-body broadcasts (arrived)
      if constexpr (decltype(doein)::value) {
        float tE = isP1 ? bt3 : (isP2 ? bt2 : t1c);
        float tN = isP0 ? t1c : 0.f;
        E = fmaf(dk1, E, fmaf(aE, bsE, fmaf(bE, bsP, fmaf(uflag, Uprev, tE))));
        I = fmaf(dk1, I, cI * bsI);
        N = fmaf(dk1, N, fmaf(pN, bsP, fmaf(qN, bsE, tN)));
      }
      // [5] V <- V(t+1) using just-updated E/I/N(t), m(t)
      float Nm = N * mm;
      float R = fmaf(E, VE, fmaf(Nm, VNMDA, fmaf(I, -VI, vngLVL)));
      float S = ((gLp + E) + I) + Nm;
      V = fmaf(DTC, fmaf(-S, V, R), V);
      // [6] ring: Q(t)->Q(t+1), deferred scatter of s(t-1)=bsP
      float nll = wrol1(Ql[0]); nll = htop ? 0.f : nll;
      float nlf = wrol1(Qf[0]); nlf = htop ? 0.f : nlf;
      float nlb = wrol1(Qb[0]); nlb = htop ? 0.f : nlb;
      Ql[0] = fmaf(Wshl[0], bsP, Ql[1]);
      Ql[1] = fmaf(Wshl[1], bsP, Ql[2]);
      Ql[2] = fmaf(Wshl[2], bsP, Ql[3]);
      Ql[3] = fmaf(Wshl[3], bsP, nll);
      Qf[0] = fmaf(Wshf[0], bsP, Qf[1]);
      Qf[1] = fmaf(Wshf[1], bsP, Qf[2]);
      Qf[2] = fmaf(Wshf[2], bsP, Qf[3]);
      Qf[3] = fmaf(Wshf[3], bsP, nlf);
      Qb[0] = fmaf(Wshb[0], bsP, Qb[1]);
      Qb[1] = fmaf(Wshb[1], bsP, Qb[2]);
      Qb[2] = fmaf(Wshb[2], bsP, Qb[3]);
      Qb[3] = fmaf(Wshb[3], bsP, nlb);
      // [7] commit deferred carries
      bsE = nbsE; bsI = nbsI; bsP = nbsP; bt2 = nbt2; bt3 = nbt3;
      t1c = t1n; Uprev = Unew;
    };
    auto advance = [&]() {
      ++stc; uidx += TRS;
      if (stc == STEPS) { stc = 0; ++trc; uidx = trc; }
    };

    // body 0: E/I/N update peeled (state already holds step-0 values)
    bodyfn(std::integral_constant<bool, false>{});
    advance();
    for (int t = 1; t < TRS * STEPS; ++t) {
      bodyfn(std::integral_constant<bool, true>{});
      if (stc == STEPS - 1) {
        if (hlane == 2) vsnap[trc * NODE + nodeF] = V;   // pop2 truth lane
      }
      advance();
    }
    return;
  }

  // ================= SLOW PATH (maxd>126): r3 core, wave w = node w ========
  {
    const float cE0s2 = cE0s - rl;
    const float cN0s2 = cN0s - rl;
    const float cE1s = -rb;
    const float cE2s = -rf;

    const int hb = node * POP * 4;
    float V0 = hx[hb + 0], V1 = hx[hb + 4], V2 = hx[hb + 8];
    float E0 = hx[hb + 1], E1 = hx[hb + 5], E2 = hx[hb + 9];
    float I0 = hx[hb + 2], I1 = hx[hb + 6], I2 = hx[hb + 10];
    float N0 = hx[hb + 3], N1 = hx[hb + 7], N2 = hx[hb + 11];

    const bool loS = (lane < 3);
    const float caL = loS ? npsL2 : namL2;
    const float cbL = loS ? psVR * L2E : 0.f;
    const float cdL = loS ? 1.f : 0.2f;
    const bool selB = (lane == 1) || (lane == 4);
    const bool selC = (lane == 2) || (lane == 5);
    const bool is63 = (lane == 63);

    float vE0s2 = cE0s2; PIN_V(vE0s2);
    float vN0s2 = cN0s2; PIN_V(vN0s2);
    float vE1e  = cE1e;  PIN_V(vE1e);
    float vE1s  = cE1s;  PIN_V(vE1s);
    float vE2e  = cE2e;  PIN_V(vE2e);
    float vE2s  = cE2s;  PIN_V(vE2s);
    float vI0   = cI0;   PIN_V(vI0);
    float vI1   = cI1;   PIN_V(vI1);
    float vN1   = cN1;   PIN_V(vN1);
    float vN2   = cN2;   PIN_V(vN2);
    float vngLVL = -gLVL; PIN_V(vngLVL);

    constexpr int NR = 8;
    float Wl[NR], Wf[NR], Wb[NR];
#pragma unroll
    for (int r = 0; r < NR; ++r) {
      int s = NR * lane + r;
      Wl[r] = Wall[wv][s];
      Wf[r] = Wall[wv][WSTR + s];
      Wb[r] = Wall[wv][2 * WSTR + s];
    }

    float Pl[NR], Pf[NR], Pb[NR], hbuf[NR];
#pragma unroll
    for (int r = 0; r < NR; ++r) { Pl[r] = 0.f; Pf[r] = 0.f; Pb[r] = 0.f; hbuf[r] = 0.f; }
    for (int d = 0; d <= maxd; ++d) {
      float wl_ = Wall[wv][d], wf_ = Wall[wv][WSTR + d], wb_ = Wall[wv][2 * WSTR + d];
#pragma unroll
      for (int r = NR - 1; r > 0; --r) hbuf[r] = hbuf[r - 1];
      int idx = d - NR * lane;
      bool ok = idx >= 0;
      float hv = hE_lds[wv][ok ? idx : 0];
      hbuf[0] = ok ? hv : 0.f;
#pragma unroll
      for (int r = 0; r < NR; ++r) {
        Pl[r] = fmaf(wl_, hbuf[r], Pl[r]);
        Pf[r] = fmaf(wf_, hbuf[r], Pf[r]);
        Pb[r] = fmaf(wb_, hbuf[r], Pb[r]);
      }
    }

    auto rotscat = [&](float* P, const float* W, float sPv) {
      float nl = is63 ? 0.f : wrol1(P[0]);
#pragma unroll
      for (int r = 0; r < NR - 1; ++r) P[r] = fmaf(W[r], sPv, P[r + 1]);
      P[NR - 1] = fmaf(W[NR - 1], sPv, nl);
    };

    for (int tr = 0; tr < TRS; ++tr) {
      float u_tr = (lane < STEPS) ? u_lds[wv][lane * TRS + tr] : 0.f;
#pragma unroll
      for (int st = 0; st < STEPS; ++st) {
        float t1 = bperm0_(Pl[0]);
        float t2 = bperm0_(Pf[0]);
        float t3 = bperm0_(Pb[0]);

        float Vs = selC ? V2 : (selB ? V1 : V0);
        float ex = __builtin_amdgcn_exp2f(fmaf(caL, Vs, cbL));
        float sg = rcp_(fmaf(cdL, ex, 1.f));
        float sE = rlane_(sg, 0), sI = rlane_(sg, 1), sP = rlane_(sg, 2);
        float m0 = rlane_(sg, 3), m1 = rlane_(sg, 4), m2 = rlane_(sg, 5);
        float U = rlane_(u_tr, st);

        float T0 = t1 + U;
        float T2 = t2 + U;
        float nE0 = fmaf(dk1, E0, fmaf(vE0s2, sP, T0));
        float nN0 = fmaf(dk1, N0, fmaf(vN0s2, sP, t1));
        float nE1 = fmaf(dk1, E1, fmaf(vE1e, sE, fmaf(vE1s, sP, t3)));
        float nN1 = fmaf(dk1, N1, vN1 * sE);
        float nE2 = fmaf(dk1, E2, fmaf(vE2e, sE, fmaf(vE2s, sP, T2)));
        float nN2 = fmaf(dk1, N2, vN2 * sE);
        float pI = vI0 * sI;
        float nI0 = fmaf(dk1, I0, pI);
        float nI1 = fmaf(dk1, I1, vI1 * sI);
        float nI2 = fmaf(dk1, I2, pI);

        float Nm0 = N0 * m0, Nm1 = N1 * m1, Nm2 = N2 * m2;
        float R0 = fmaf(E0, VE, fmaf(Nm0, VNMDA, fmaf(I0, -VI, vngLVL)));
        float R1 = fmaf(E1, VE, fmaf(Nm1, VNMDA, fmaf(I1, -VI, vngLVL)));
        float R2 = fmaf(E2, VE, fmaf(Nm2, VNMDA, fmaf(I2, -VI, vngLVL)));
        float S0 = gLp + E0 + I0 + Nm0;
        float S1 = gLp + E1 + I1 + Nm1;
        float S2 = gLp + E2 + I2 + Nm2;
        V0 = fmaf(DTC, fmaf(-S0, V0, R0), V0);
        V1 = fmaf(DTC, fmaf(-S1, V1, R1), V1);
        V2 = fmaf(DTC, fmaf(-S2, V2, R2), V2);
        E0 = nE0; E1 = nE1; E2 = nE2;
        I0 = nI0; I1 = nI1; I2 = nI2;
        N0 = nN0; N1 = nN1; N2 = nN2;

        rotscat(Pl, Wl, sP);
        rotscat(Pf, Wf, sP);
        rotscat(Pb, Wb, sP);
      }
      if (lane == 0) vsnap[tr * NODE + node] = V2;
    }
  }
}

// ---------------------------------------------------------------------------
// Kernel C: EEG readout. cm elimination: sum((lm-cm)@v) = a_o - mean_o(a_o).
// ---------------------------------------------------------------------------
__global__ __launch_bounds__(256) void eeg_kernel(
    const float* __restrict__ lm, const float* __restrict__ vsnap,
    const float* __restrict__ theta, float* __restrict__ out) {
  int tr = blockIdx.x;
  __shared__ float vs[NODE];
  __shared__ float partl[4][OUT];
  int tid = threadIdx.x;
  for (int n = tid; n < NODE; n += 256) vs[n] = vsnap[tr * NODE + n];
  __syncthreads();
  int o = tid & 63, w = tid >> 6;
  float acc = 0.f;
  for (int n = w * 100; n < w * 100 + 100; ++n)
    acc = fmaf(lm[o * NODE + n], vs[n], acc);
  partl[w][o] = acc;
  __syncthreads();
  if (tid < OUT) {
    float cy0 = theta[22], y0 = theta[19];
    float a = partl[0][tid] + partl[1][tid] + partl[2][tid] + partl[3][tid];
    float mean = wave_reduce1(a) * (1.f / OUT);
    out[tr * OUT + tid] = cy0 * (a - mean) - y0;
  }
}

extern "C" void kernel_launch(void* const* d_in, const int* in_sizes, int n_in,
                              void* d_out, int out_size, void* d_ws, size_t ws_size,
                              hipStream_t stream) {
  const float* external = (const float*)d_in[0];
  const float* hx       = (const float*)d_in[1];
  const float* hE       = (const float*)d_in[2];
  const float* sc       = (const float*)d_in[3];
  const float* dist     = (const float*)d_in[4];
  const float* wbb      = (const float*)d_in[5];
  const float* wff      = (const float*)d_in[6];
  const float* wll      = (const float*)d_in[7];
  const float* lm       = (const float*)d_in[8];
  const float* theta    = (const float*)d_in[9];
  float* out = (float*)d_out;

  float* vsnap = (float*)d_ws;               // TRS*NODE
  float* part  = vsnap + TRS * NODE;         // 3*64 ssq partials

  ssq_kernel<<<64, 256, 0, stream>>>(wbb, wff, wll, sc, part);
  sim_kernel<<<NODE / 2, 128, 0, stream>>>(external, hx, hE, sc, dist, wbb, wff,
                                           wll, theta, part, vsnap);
  eeg_kernel<<<TRS, 256, 0, stream>>>(lm, vsnap, theta, out);
}

// Round 8
// 145.893 us; speedup vs baseline: 3.0710x; 3.0710x over previous
//
#include <hip/hip_runtime.h>
#include <type_traits>

#define NODE 400
#define POP 3
#define TRS 40
#define STEPS 10
#define DMAX 500
#define OUT 64
#define DT 0.1f
#define JPL 7           // ceil(NODE/64) j-indices per lane
#define WSTR 512        // per-stream W bin stride (delta in [0,511])

__device__ __forceinline__ float relu_(float x) { return x > 0.f ? x : 0.f; }
__device__ __forceinline__ float rcp_(float x) { return __builtin_amdgcn_rcpf(x); }
__device__ __forceinline__ float rlane_(float v, int l) {
  return __builtin_bit_cast(float, __builtin_amdgcn_readlane(__builtin_bit_cast(int, v), l));
}
// broadcast lane 0 to all lanes, VGPR result (slow-path harvest)
__device__ __forceinline__ float bperm0_(float v) {
  return __builtin_bit_cast(float,
      __builtin_amdgcn_ds_bpermute(0, __builtin_bit_cast(int, v)));
}
// ds_swizzle BitMode: src_lane = ((lane & and) | or) ^ xor within each
// 32-lane group. OFF = (xor<<10)|(or<<5)|and. and=0,xor=0 -> every lane reads
// lane 'or' of its OWN 32-group (half-local broadcast). Verified r4-r7.
template <int OFF>
__device__ __forceinline__ float swz_(float v) {
  return __builtin_bit_cast(float,
      __builtin_amdgcn_ds_swizzle(__builtin_bit_cast(int, v), OFF));
}
// pin a value into a VGPR
#define PIN_V(x) asm volatile("" : "+v"(x))

// ---- DPP helpers
template <int CTRL>
__device__ __forceinline__ float dpp_mov(float x) {
  int r = __builtin_amdgcn_update_dpp(0, __builtin_bit_cast(int, x), CTRL,
                                      0xf, 0xf, true);
  return __builtin_bit_cast(float, r);
}
template <int CTRL>
__device__ __forceinline__ int dpp_movi(int x) {
  return __builtin_amdgcn_update_dpp(0, x, CTRL, 0xf, 0xf, true);
}
// wave rotate: dst[L] = src[(L+1) & 63]  (wave_rol:1 = 0x134, verified r1-r7)
__device__ __forceinline__ float wrol1(float x) { return dpp_mov<0x134>(x); }

__device__ __forceinline__ void wave_reduce3(float& a, float& b, float& c) {
  a += dpp_mov<0x111>(a); b += dpp_mov<0x111>(b); c += dpp_mov<0x111>(c);
  a += dpp_mov<0x112>(a); b += dpp_mov<0x112>(b); c += dpp_mov<0x112>(c);
  a += dpp_mov<0x114>(a); b += dpp_mov<0x114>(b); c += dpp_mov<0x114>(c);
  a += dpp_mov<0x118>(a); b += dpp_mov<0x118>(b); c += dpp_mov<0x118>(c);
  a += dpp_mov<0x142>(a); b += dpp_mov<0x142>(b); c += dpp_mov<0x142>(c);
  a += dpp_mov<0x143>(a); b += dpp_mov<0x143>(b); c += dpp_mov<0x143>(c);
  a = rlane_(a, 63); b = rlane_(b, 63); c = rlane_(c, 63);
}

__device__ __forceinline__ float wave_reduce1(float a) {
  a += dpp_mov<0x111>(a); a += dpp_mov<0x112>(a); a += dpp_mov<0x114>(a);
  a += dpp_mov<0x118>(a); a += dpp_mov<0x142>(a); a += dpp_mov<0x143>(a);
  return rlane_(a, 63);
}

__device__ __forceinline__ int wave_max_int(int x) {
  x = max(x, dpp_movi<0x111>(x));
  x = max(x, dpp_movi<0x112>(x));
  x = max(x, dpp_movi<0x114>(x));
  x = max(x, dpp_movi<0x118>(x));
  x = max(x, dpp_movi<0x142>(x));
  x = max(x, dpp_movi<0x143>(x));
  return __builtin_amdgcn_readlane(x, 63);
}

// ---------------------------------------------------------------------------
// Kernel A: Frobenius sum-of-squares partials (64 blocks, no atomics).
// ---------------------------------------------------------------------------
__global__ __launch_bounds__(256) void ssq_kernel(
    const float* __restrict__ wbb, const float* __restrict__ wff,
    const float* __restrict__ wll, const float* __restrict__ sc,
    float* __restrict__ part) {
  float eb = 0.f, ef = 0.f, el = 0.f;
  for (int idx = blockIdx.x * 256 + threadIdx.x; idx < NODE * NODE;
       idx += 64 * 256) {
    int i = idx / NODE, j = idx - i * NODE;
    int ji = j * NODE + i;
    float scij = sc[idx];
    float b = expf(wbb[idx]) * scij;
    float f = expf(wff[idx]) * scij;
    float l = 0.5f * (expf(wll[idx]) * scij + expf(wll[ji]) * sc[ji]);
    eb = fmaf(b, b, eb); ef = fmaf(f, f, ef); el = fmaf(l, l, el);
  }
  wave_reduce3(eb, ef, el);
  __shared__ float red[3][4];
  int lane = threadIdx.x & 63, wv = threadIdx.x >> 6;
  if (lane == 0) { red[0][wv] = eb; red[1][wv] = ef; red[2][wv] = el; }
  __syncthreads();
  if (threadIdx.x == 0) {
    part[blockIdx.x]       = red[0][0] + red[0][1] + red[0][2] + red[0][3];
    part[64 + blockIdx.x]  = red[1][0] + red[1][1] + red[1][2] + red[1][3];
    part[128 + blockIdx.x] = red[2][0] + red[2][1] + red[2][2] + red[2][3];
  }
}

// ---------------------------------------------------------------------------
// Kernel B fast path (r8): r7's pop-split + fully-deferred schedule
// (correctness-verified), restructured compiler-friendly:
//  - NO lambdas (r7's by-ref-capture lambda materialized -> scratch traffic,
//    WRITE_SIZE 250->7800 KB)
//  - nested tr/st loops, #pragma unroll STEPS -> 10-body window so the 5
//    deferred swizzles/body are truly hidden via register rotation
//  - uniform body: first-body E/I/N peel replaced by EXACT state
//    pre-distortion  E=(E0-bE*hE0)/dk1, I=I0/dk1, N=(N0-pN*hE0)/dk1
//    with initial carries {bsE=bsI=0, bsP=hE0, bt2=bt3=t1c=0, Uprev=0}.
// ---------------------------------------------------------------------------
__global__ __launch_bounds__(128) void sim_kernel(
    const float* __restrict__ external, const float* __restrict__ hx,
    const float* __restrict__ hE, const float* __restrict__ sc,
    const float* __restrict__ dist, const float* __restrict__ wbb,
    const float* __restrict__ wff, const float* __restrict__ wll,
    const float* __restrict__ theta, const float* __restrict__ part,
    float* __restrict__ vsnap) {
  const int wv = threadIdx.x >> 6;
  const int lane = threadIdx.x & 63;
  const int node = blockIdx.x * 2 + wv;   // this wave's setup node

  __shared__ float Wall[2][3 * WSTR];   // per node: Wl | Wf | Wb (pre-scaled)
  __shared__ float hE_lds[2][DMAX];
  __shared__ float u_lds[2][STEPS * TRS];
  __shared__ float sc_c[2][3];          // rl, rf, rb (scaled row sums)
  __shared__ int   sc_md[2];            // per-node maxd

  // --- global norm sums from ssq partials (one DPP reduce) ---
  float sb = part[lane], sf = part[64 + lane], sl = part[128 + lane];
  wave_reduce3(sb, sf, sl);
  const float inv_nb = 1.f / sqrtf(sb);
  const float inv_nf = 1.f / sqrtf(sf);
  const float inv_nl = 1.f / sqrtf(sl);

  // --- parameters ---
  const float VL = relu_(theta[0]), VI = relu_(theta[1]);
  const float VE = relu_(theta[2]), VNMDA = relu_(theta[3]);
  const float alpha_mg = relu_(theta[4]), VR = relu_(theta[5]);
  const float pi_sigma = relu_(theta[6]);
  const float gLp = relu_(theta[7]), Cc = relu_(theta[8]), kappa = relu_(theta[9]);
  const float g_gE = relu_(theta[10]), g_gE_sc = relu_(theta[11]);
  const float g_gI = relu_(theta[12]), g_gI_sc = relu_(theta[13]);
  const float g_gN = relu_(theta[14]), g_gN_sc = relu_(theta[15]);
  const float g_k = relu_(theta[16]);
  const float mu = 0.1f + relu_(theta[20]);
  const float uk = relu_(theta[21]) * theta[23];
  const float g_l = relu_(theta[24]), g_f = relu_(theta[25]), g_b = relu_(theta[26]);
  const float DTC = DT / Cc;
  const float dk = DT * kappa;
  const float nps = -pi_sigma, psVR = pi_sigma * VR;
  const float nam = -alpha_mg;

  const float dk1  = 1.f - dk;
  const float cA   = dk * g_l;     // folded into Wl bins
  const float cF   = dk * g_f;     // folded into Wf bins
  const float cB   = dk * g_b;     // folded into Wb bins
  const float cE0s = dk * g_gE;
  const float cE1e = dk * g_gE_sc;
  const float cE2e = dk * g_k;
  const float cI0  = dk * g_gI;
  const float cI1  = dk * g_gI_sc;
  const float cN0s = dk * g_gN;
  const float cN1  = dk * g_gN_sc;
  const float cN2  = dk * g_gN;
  const float gLVL = gLp * VL;
  const float L2E = 1.44269504088896f;
  const float npsL2 = nps * L2E;
  const float namL2 = nam * L2E;

  // --- stage LDS (wave w handles node w's slabs) ---
  for (int k = lane; k < 3 * WSTR; k += 64) Wall[wv][k] = 0.f;
  for (int d = lane; d < DMAX; d += 64) hE_lds[wv][d] = hE[node * DMAX + d];
  const float ukdk = dk * uk;
  for (int t = lane; t < STEPS * TRS; t += 64)
    u_lds[wv][t] = ukdk * external[node * STEPS * TRS + t];

  // --- bin weights by delay (pre-scaled), row sums, max delay ---
  const float scl = inv_nl * cA, scf = inv_nf * cF, scb = inv_nb * cB;
  float rl = 0.f, rf = 0.f, rb = 0.f;
  int mymax = 0;
#pragma unroll
  for (int kj = 0; kj < JPL; ++kj) {
    int j = lane + kj * 64;
    if (j < NODE) {
      int ij = node * NODE + j;
      int ji = j * NODE + node;
      float scij = sc[ij];
      float vb = expf(wbb[ij]) * scij * scb;
      float vf = expf(wff[ij]) * scij * scf;
      float vl = 0.5f * (expf(wll[ij]) * scij + expf(wll[ji]) * sc[ji]) * scl;
      int dd = (int)(dist[ij] / mu);
      dd = min(max(dd, 0), DMAX - 1);
      atomicAdd(&Wall[wv][dd], vl);
      atomicAdd(&Wall[wv][WSTR + dd], vf);
      atomicAdd(&Wall[wv][2 * WSTR + dd], vb);
      rl += vl; rf += vf; rb += vb;
      mymax = max(mymax, dd);
    }
  }
  wave_reduce3(rl, rf, rb);
  const int maxd_w = wave_max_int(mymax);
  if (lane == 0) {
    sc_c[wv][0] = rl; sc_c[wv][1] = rf; sc_c[wv][2] = rb;
    sc_md[wv] = maxd_w;
  }
  __syncthreads();
  const int maxd = max(sc_md[0], sc_md[1]);

  if (maxd <= 126) {
    // ================= FAST PATH: wave 0 only, pop-split halves ============
    if (wv != 0) return;
    const int h = lane >> 5, hlane = lane & 31;
    const int nodeF = blockIdx.x * 2 + h;
    const int p3 = hlane % 3;             // owned population (truth: hlane<3)
    const bool isP1 = (p3 == 1), isP2 = (p3 == 2), isP0 = (p3 == 0);

    // per-half (per-node) scalars
    const float rlh = sc_c[h][0], rfh = sc_c[h][1], rbh = sc_c[h][2];
    const float cE0s2 = cE0s - rlh;
    const float cN0s2 = cN0s - rlh;
    const float cE1s = -rbh;
    const float cE2s = -rfh;
    // per-pop coefficient registers (VGPR; uniform dyn instruction stream)
    const float aE = isP1 ? cE1e : (isP2 ? cE2e : 0.f);
    const float bE = isP1 ? cE1s : (isP2 ? cE2s : cE0s2);
    const float uflag = isP1 ? 0.f : 1.f;
    const float cI = isP1 ? cI1 : cI0;
    const float pN = isP0 ? cN0s2 : 0.f;
    const float qN = isP1 ? cN1 : (isP2 ? cN2 : 0.f);
    float vngLVL = -gLVL;       PIN_V(vngLVL);
    float vpsVRL2 = psVR * L2E; PIN_V(vpsVRL2);

    const bool htop = (hlane == 31);
    constexpr int NR = 4;

    // shifted weights (deferred ring) + W0 bin values + hE[0]
    float Wshl[NR], Wshf[NR], Wshb[NR];
    const float W0l = Wall[h][0], W0f = Wall[h][WSTR], W0b = Wall[h][2 * WSTR];
    const float hE0 = hE_lds[h][0];
#pragma unroll
    for (int r = 0; r < NR; ++r) {
      int s = NR * hlane + r + 1;          // W[slot+1]; slot127->W[128]=0 ok
      Wshl[r] = Wall[h][s];
      Wshf[r] = Wall[h][WSTR + s];
      Wshb[r] = Wall[h][2 * WSTR + s];
    }

    // own-pop state; EXACT pre-distortion so the uniform body's first
    // E/I/N update (with initial carries) reproduces E(0),I(0),N(0).
    const float inv_dk1 = 1.f / dk1;
    const int hb = nodeF * POP * 4 + 4 * p3;
    float V = hx[hb + 0];
    float E = (hx[hb + 1] - bE * hE0) * inv_dk1;
    float I = hx[hb + 2] * inv_dk1;
    float N = (hx[hb + 3] - pN * hE0) * inv_dk1;

    // prologue: P0[slot] = sum_{d>=slot} W[d]*hE[d-slot]
    float Ql[NR], Qf[NR], Qb[NR], hbuf[NR];
#pragma unroll
    for (int r = 0; r < NR; ++r) { Ql[r] = 0.f; Qf[r] = 0.f; Qb[r] = 0.f; hbuf[r] = 0.f; }
    for (int d = 0; d <= maxd; ++d) {
      float wl_ = Wall[h][d], wf_ = Wall[h][WSTR + d], wb_ = Wall[h][2 * WSTR + d];
#pragma unroll
      for (int r = NR - 1; r > 0; --r) hbuf[r] = hbuf[r - 1];
      int idx = d - NR * hlane;
      bool ok = idx >= 0;
      float hv = hE_lds[h][ok ? idx : 0];
      hbuf[0] = ok ? hv : 0.f;
#pragma unroll
      for (int r = 0; r < NR; ++r) {
        Ql[r] = fmaf(wl_, hbuf[r], Ql[r]);
        Qf[r] = fmaf(wf_, hbuf[r], Qf[r]);
        Qb[r] = fmaf(wb_, hbuf[r], Qb[r]);
      }
    }
    // Q0 = P0 - W[slot]*hE0 (convert to deferred-scatter state)
#pragma unroll
    for (int r = 0; r < NR; ++r) {
      int s = NR * hlane + r;
      Ql[r] = fmaf(-Wall[h][s], hE0, Ql[r]);
      Qf[r] = fmaf(-Wall[h][WSTR + s], hE0, Qf[r]);
      Qb[r] = fmaf(-Wall[h][2 * WSTR + s], hE0, Qb[r]);
    }

    const float* uh = &u_lds[h][0];
    // deferred carries (produced at body t-1, consumed at body t)
    float bsE = 0.f, bsI = 0.f, bsP = hE0;   // sigma(t-1); s(-1)=hE[0]
    float bt2 = 0.f, bt3 = 0.f, t1c = 0.f, carryU = 0.f;

    for (int tr = 0; tr < TRS; ++tr) {
      float uu[STEPS];
#pragma unroll
      for (int s2 = 0; s2 < STEPS; ++s2) uu[s2] = uh[s2 * TRS + tr];
#pragma unroll
      for (int st = 0; st < STEPS; ++st) {
        float Uprev = (st == 0) ? carryU : uu[st - 1];   // static select
        // [1] own-pop sigma(t), m(t) from V(t)
        float sg = rcp_(1.f + __builtin_amdgcn_exp2f(fmaf(npsL2, V, vpsVRL2)));
        float mm = rcp_(fmaf(0.2f, __builtin_amdgcn_exp2f(namL2 * V), 1.f));
        // [2] harvest a(t) = Q[0] + W0*s(t-1)  (local regs; pre-ring)
        float t1n = fmaf(W0l, bsP, Ql[0]);
        float t2n = fmaf(W0f, bsP, Qf[0]);
        float t3n = fmaf(W0b, bsP, Qb[0]);
        // [3] issue next-body cross-lane traffic (consumed at body t+1)
        float nbsE = swz_<(0 << 5)>(sg);     // hlane0 = sigmaE
        float nbsI = swz_<(1 << 5)>(sg);     // hlane1 = sigmaI
        float nbsP = swz_<(2 << 5)>(sg);     // hlane2 = sigmaP
        float nbt2 = swz_<(0 << 5)>(t2n);    // from lane 0
        float nbt3 = swz_<(0 << 5)>(t3n);
        __builtin_amdgcn_sched_barrier(0);
        // [4] E/I/N <- step-t values using PREV-body carries (arrived)
        {
          float tE = isP1 ? bt3 : (isP2 ? bt2 : t1c);
          float tN = isP0 ? t1c : 0.f;
          E = fmaf(dk1, E, fmaf(aE, bsE, fmaf(bE, bsP, fmaf(uflag, Uprev, tE))));
          I = fmaf(dk1, I, cI * bsI);
          N = fmaf(dk1, N, fmaf(pN, bsP, fmaf(qN, bsE, tN)));
        }
        // [5] V <- V(t+1) using just-updated E/I/N(t), m(t)
        float Nm = N * mm;
        float R = fmaf(E, VE, fmaf(Nm, VNMDA, fmaf(I, -VI, vngLVL)));
        float S = ((gLp + E) + I) + Nm;
        V = fmaf(DTC, fmaf(-S, V, R), V);
        // [6] ring: Q(t)->Q(t+1), deferred scatter of s(t-1)=bsP
        float nll = wrol1(Ql[0]); nll = htop ? 0.f : nll;
        float nlf = wrol1(Qf[0]); nlf = htop ? 0.f : nlf;
        float nlb = wrol1(Qb[0]); nlb = htop ? 0.f : nlb;
        Ql[0] = fmaf(Wshl[0], bsP, Ql[1]);
        Ql[1] = fmaf(Wshl[1], bsP, Ql[2]);
        Ql[2] = fmaf(Wshl[2], bsP, Ql[3]);
        Ql[3] = fmaf(Wshl[3], bsP, nll);
        Qf[0] = fmaf(Wshf[0], bsP, Qf[1]);
        Qf[1] = fmaf(Wshf[1], bsP, Qf[2]);
        Qf[2] = fmaf(Wshf[2], bsP, Qf[3]);
        Qf[3] = fmaf(Wshf[3], bsP, nlf);
        Qb[0] = fmaf(Wshb[0], bsP, Qb[1]);
        Qb[1] = fmaf(Wshb[1], bsP, Qb[2]);
        Qb[2] = fmaf(Wshb[2], bsP, Qb[3]);
        Qb[3] = fmaf(Wshb[3], bsP, nlb);
        // [7] commit deferred carries (register renames in unrolled window)
        bsE = nbsE; bsI = nbsI; bsP = nbsP; bt2 = nbt2; bt3 = nbt3;
        t1c = t1n;
      }
      carryU = uu[STEPS - 1];
      if (hlane == 2) vsnap[tr * NODE + nodeF] = V;   // pop2 truth lane
    }
    return;
  }

  // ================= SLOW PATH (maxd>126): r3 core, wave w = node w ========
  {
    const float cE0s2 = cE0s - rl;
    const float cN0s2 = cN0s - rl;
    const float cE1s = -rb;
    const float cE2s = -rf;

    const int hb = node * POP * 4;
    float V0 = hx[hb + 0], V1 = hx[hb + 4], V2 = hx[hb + 8];
    float E0 = hx[hb + 1], E1 = hx[hb + 5], E2 = hx[hb + 9];
    float I0 = hx[hb + 2], I1 = hx[hb + 6], I2 = hx[hb + 10];
    float N0 = hx[hb + 3], N1 = hx[hb + 7], N2 = hx[hb + 11];

    const bool loS = (lane < 3);
    const float caL = loS ? npsL2 : namL2;
    const float cbL = loS ? psVR * L2E : 0.f;
    const float cdL = loS ? 1.f : 0.2f;
    const bool selB = (lane == 1) || (lane == 4);
    const bool selC = (lane == 2) || (lane == 5);
    const bool is63 = (lane == 63);

    float vE0s2 = cE0s2; PIN_V(vE0s2);
    float vN0s2 = cN0s2; PIN_V(vN0s2);
    float vE1e  = cE1e;  PIN_V(vE1e);
    float vE1s  = cE1s;  PIN_V(vE1s);
    float vE2e  = cE2e;  PIN_V(vE2e);
    float vE2s  = cE2s;  PIN_V(vE2s);
    float vI0   = cI0;   PIN_V(vI0);
    float vI1   = cI1;   PIN_V(vI1);
    float vN1   = cN1;   PIN_V(vN1);
    float vN2   = cN2;   PIN_V(vN2);
    float vngLVL = -gLVL; PIN_V(vngLVL);

    constexpr int NR = 8;
    float Wl[NR], Wf[NR], Wb[NR];
#pragma unroll
    for (int r = 0; r < NR; ++r) {
      int s = NR * lane + r;
      Wl[r] = Wall[wv][s];
      Wf[r] = Wall[wv][WSTR + s];
      Wb[r] = Wall[wv][2 * WSTR + s];
    }

    float Pl[NR], Pf[NR], Pb[NR], hbuf[NR];
#pragma unroll
    for (int r = 0; r < NR; ++r) { Pl[r] = 0.f; Pf[r] = 0.f; Pb[r] = 0.f; hbuf[r] = 0.f; }
    for (int d = 0; d <= maxd; ++d) {
      float wl_ = Wall[wv][d], wf_ = Wall[wv][WSTR + d], wb_ = Wall[wv][2 * WSTR + d];
#pragma unroll
      for (int r = NR - 1; r > 0; --r) hbuf[r] = hbuf[r - 1];
      int idx = d - NR * lane;
      bool ok = idx >= 0;
      float hv = hE_lds[wv][ok ? idx : 0];
      hbuf[0] = ok ? hv : 0.f;
#pragma unroll
      for (int r = 0; r < NR; ++r) {
        Pl[r] = fmaf(wl_, hbuf[r], Pl[r]);
        Pf[r] = fmaf(wf_, hbuf[r], Pf[r]);
        Pb[r] = fmaf(wb_, hbuf[r], Pb[r]);
      }
    }

    auto rotscat = [&](float* P, const float* W, float sPv) {
      float nl = is63 ? 0.f : wrol1(P[0]);
#pragma unroll
      for (int r = 0; r < NR - 1; ++r) P[r] = fmaf(W[r], sPv, P[r + 1]);
      P[NR - 1] = fmaf(W[NR - 1], sPv, nl);
    };

    for (int tr = 0; tr < TRS; ++tr) {
      float u_tr = (lane < STEPS) ? u_lds[wv][lane * TRS + tr] : 0.f;
#pragma unroll
      for (int st = 0; st < STEPS; ++st) {
        float t1 = bperm0_(Pl[0]);
        float t2 = bperm0_(Pf[0]);
        float t3 = bperm0_(Pb[0]);

        float Vs = selC ? V2 : (selB ? V1 : V0);
        float ex = __builtin_amdgcn_exp2f(fmaf(caL, Vs, cbL));
        float sg = rcp_(fmaf(cdL, ex, 1.f));
        float sE = rlane_(sg, 0), sI = rlane_(sg, 1), sP = rlane_(sg, 2);
        float m0 = rlane_(sg, 3), m1 = rlane_(sg, 4), m2 = rlane_(sg, 5);
        float U = rlane_(u_tr, st);

        float T0 = t1 + U;
        float T2 = t2 + U;
        float nE0 = fmaf(dk1, E0, fmaf(vE0s2, sP, T0));
        float nN0 = fmaf(dk1, N0, fmaf(vN0s2, sP, t1));
        float nE1 = fmaf(dk1, E1, fmaf(vE1e, sE, fmaf(vE1s, sP, t3)));
        float nN1 = fmaf(dk1, N1, vN1 * sE);
        float nE2 = fmaf(dk1, E2, fmaf(vE2e, sE, fmaf(vE2s, sP, T2)));
        float nN2 = fmaf(dk1, N2, vN2 * sE);
        float pI = vI0 * sI;
        float nI0 = fmaf(dk1, I0, pI);
        float nI1 = fmaf(dk1, I1, vI1 * sI);
        float nI2 = fmaf(dk1, I2, pI);

        float Nm0 = N0 * m0, Nm1 = N1 * m1, Nm2 = N2 * m2;
        float R0 = fmaf(E0, VE, fmaf(Nm0, VNMDA, fmaf(I0, -VI, vngLVL)));
        float R1 = fmaf(E1, VE, fmaf(Nm1, VNMDA, fmaf(I1, -VI, vngLVL)));
        float R2 = fmaf(E2, VE, fmaf(Nm2, VNMDA, fmaf(I2, -VI, vngLVL)));
        float S0 = gLp + E0 + I0 + Nm0;
        float S1 = gLp + E1 + I1 + Nm1;
        float S2 = gLp + E2 + I2 + Nm2;
        V0 = fmaf(DTC, fmaf(-S0, V0, R0), V0);
        V1 = fmaf(DTC, fmaf(-S1, V1, R1), V1);
        V2 = fmaf(DTC, fmaf(-S2, V2, R2), V2);
        E0 = nE0; E1 = nE1; E2 = nE2;
        I0 = nI0; I1 = nI1; I2 = nI2;
        N0 = nN0; N1 = nN1; N2 = nN2;

        rotscat(Pl, Wl, sP);
        rotscat(Pf, Wf, sP);
        rotscat(Pb, Wb, sP);
      }
      if (lane == 0) vsnap[tr * NODE + node] = V2;
    }
  }
}

// ---------------------------------------------------------------------------
// Kernel C: EEG readout. cm elimination: sum((lm-cm)@v) = a_o - mean_o(a_o).
// ---------------------------------------------------------------------------
__global__ __launch_bounds__(256) void eeg_kernel(
    const float* __restrict__ lm, const float* __restrict__ vsnap,
    const float* __restrict__ theta, float* __restrict__ out) {
  int tr = blockIdx.x;
  __shared__ float vs[NODE];
  __shared__ float partl[4][OUT];
  int tid = threadIdx.x;
  for (int n = tid; n < NODE; n += 256) vs[n] = vsnap[tr * NODE + n];
  __syncthreads();
  int o = tid & 63, w = tid >> 6;
  float acc = 0.f;
  for (int n = w * 100; n < w * 100 + 100; ++n)
    acc = fmaf(lm[o * NODE + n], vs[n], acc);
  partl[w][o] = acc;
  __syncthreads();
  if (tid < OUT) {
    float cy0 = theta[22], y0 = theta[19];
    float a = partl[0][tid] + partl[1][tid] + partl[2][tid] + partl[3][tid];
    float mean = wave_reduce1(a) * (1.f / OUT);
    out[tr * OUT + tid] = cy0 * (a - mean) - y0;
  }
}

extern "C" void kernel_launch(void* const* d_in, const int* in_sizes, int n_in,
                              void* d_out, int out_size, void* d_ws, size_t ws_size,
                              hipStream_t stream) {
  const float* external = (const float*)d_in[0];
  const float* hx       = (const float*)d_in[1];
  const float* hE       = (const float*)d_in[2];
  const float* sc       = (const float*)d_in[3];
  const float* dist     = (const float*)d_in[4];
  const float* wbb      = (const float*)d_in[5];
  const float* wff      = (const float*)d_in[6];
  const float* wll      = (const float*)d_in[7];
  const float* lm       = (const float*)d_in[8];
  const float* theta    = (const float*)d_in[9];
  float* out = (float*)d_out;

  float* vsnap = (float*)d_ws;               // TRS*NODE
  float* part  = vsnap + TRS * NODE;         // 3*64 ssq partials

  ssq_kernel<<<64, 256, 0, stream>>>(wbb, wff, wll, sc, part);
  sim_kernel<<<NODE / 2, 128, 0, stream>>>(external, hx, hE, sc, dist, wbb, wff,
                                           wll, theta, part, vsnap);
  eeg_kernel<<<TRS, 256, 0, stream>>>(lm, vsnap, theta, out);
}

// Round 9
// 137.291 us; speedup vs baseline: 3.2634x; 1.0627x over previous
//
#include <hip/hip_runtime.h>
#include <type_traits>

#define NODE 400
#define POP 3
#define TRS 40
#define STEPS 10
#define DMAX 500
#define OUT 64
#define DT 0.1f
#define JPL 7           // ceil(NODE/64) j-indices per lane
#define WSTR 512        // per-stream W bin stride (delta in [0,511])

__device__ __forceinline__ float relu_(float x) { return x > 0.f ? x : 0.f; }
__device__ __forceinline__ float rcp_(float x) { return __builtin_amdgcn_rcpf(x); }
__device__ __forceinline__ float rlane_(float v, int l) {
  return __builtin_bit_cast(float, __builtin_amdgcn_readlane(__builtin_bit_cast(int, v), l));
}
// broadcast lane 0 to all lanes, VGPR result (slow-path harvest)
__device__ __forceinline__ float bperm0_(float v) {
  return __builtin_bit_cast(float,
      __builtin_amdgcn_ds_bpermute(0, __builtin_bit_cast(int, v)));
}
// pin a value into a VGPR
#define PIN_V(x) asm volatile("" : "+v"(x))

// ---- DPP helpers
template <int CTRL>
__device__ __forceinline__ float dpp_mov(float x) {
  int r = __builtin_amdgcn_update_dpp(0, __builtin_bit_cast(int, x), CTRL,
                                      0xf, 0xf, true);
  return __builtin_bit_cast(float, r);
}
template <int CTRL>
__device__ __forceinline__ int dpp_movi(int x) {
  return __builtin_amdgcn_update_dpp(0, x, CTRL, 0xf, 0xf, true);
}
// wave rotate: dst[L] = src[(L+1) & 63]  (wave_rol:1 = 0x134, verified r1-r8)
__device__ __forceinline__ float wrol1(float x) { return dpp_mov<0x134>(x); }

__device__ __forceinline__ void wave_reduce3(float& a, float& b, float& c) {
  a += dpp_mov<0x111>(a); b += dpp_mov<0x111>(b); c += dpp_mov<0x111>(c);
  a += dpp_mov<0x112>(a); b += dpp_mov<0x112>(b); c += dpp_mov<0x112>(c);
  a += dpp_mov<0x114>(a); b += dpp_mov<0x114>(b); c += dpp_mov<0x114>(c);
  a += dpp_mov<0x118>(a); b += dpp_mov<0x118>(b); c += dpp_mov<0x118>(c);
  a += dpp_mov<0x142>(a); b += dpp_mov<0x142>(b); c += dpp_mov<0x142>(c);
  a += dpp_mov<0x143>(a); b += dpp_mov<0x143>(b); c += dpp_mov<0x143>(c);
  a = rlane_(a, 63); b = rlane_(b, 63); c = rlane_(c, 63);
}

__device__ __forceinline__ float wave_reduce1(float a) {
  a += dpp_mov<0x111>(a); a += dpp_mov<0x112>(a); a += dpp_mov<0x114>(a);
  a += dpp_mov<0x118>(a); a += dpp_mov<0x142>(a); a += dpp_mov<0x143>(a);
  return rlane_(a, 63);
}

__device__ __forceinline__ int wave_max_int(int x) {
  x = max(x, dpp_movi<0x111>(x));
  x = max(x, dpp_movi<0x112>(x));
  x = max(x, dpp_movi<0x114>(x));
  x = max(x, dpp_movi<0x118>(x));
  x = max(x, dpp_movi<0x142>(x));
  x = max(x, dpp_movi<0x143>(x));
  return __builtin_amdgcn_readlane(x, 63);
}

// ---------------------------------------------------------------------------
// Kernel A: Frobenius sum-of-squares partials (64 blocks, no atomics).
// ---------------------------------------------------------------------------
__global__ __launch_bounds__(256) void ssq_kernel(
    const float* __restrict__ wbb, const float* __restrict__ wff,
    const float* __restrict__ wll, const float* __restrict__ sc,
    float* __restrict__ part) {
  float eb = 0.f, ef = 0.f, el = 0.f;
  for (int idx = blockIdx.x * 256 + threadIdx.x; idx < NODE * NODE;
       idx += 64 * 256) {
    int i = idx / NODE, j = idx - i * NODE;
    int ji = j * NODE + i;
    float scij = sc[idx];
    float b = expf(wbb[idx]) * scij;
    float f = expf(wff[idx]) * scij;
    float l = 0.5f * (expf(wll[idx]) * scij + expf(wll[ji]) * sc[ji]);
    eb = fmaf(b, b, eb); ef = fmaf(f, f, ef); el = fmaf(l, l, el);
  }
  wave_reduce3(eb, ef, el);
  __shared__ float red[3][4];
  int lane = threadIdx.x & 63, wv = threadIdx.x >> 6;
  if (lane == 0) { red[0][wv] = eb; red[1][wv] = ef; red[2][wv] = el; }
  __syncthreads();
  if (threadIdx.x == 0) {
    part[blockIdx.x]       = red[0][0] + red[0][1] + red[0][2] + red[0][3];
    part[64 + blockIdx.x]  = red[1][0] + red[1][1] + red[1][2] + red[1][3];
    part[128 + blockIdx.x] = red[2][0] + red[2][1] + red[2][2] + red[2][3];
  }
}

// ---------------------------------------------------------------------------
// Kernel B fast path (r9): ONE node per WAVE (both waves active), pop-split
// p = lane%3 across the full wave. Cross-lane traffic = v_readlane -> SGPR
// (no LDS on the recurrence cycle; r8's 5 ds_swizzles were the residual
// ~240cy/step). Every lane tracks its pop EXACTLY (own state + wave-uniform
// SGPR broadcasts + per-lane VGPR coefficients -> all ops <=1 SGPR operand).
// Ring: 64 lanes x NR=2 regs = 128 slots, deferred-scatter form (r8-proven):
// shift-by-1 weights, W0-corrected harvest, exact state pre-distortion.
// ---------------------------------------------------------------------------
__global__ __launch_bounds__(128) void sim_kernel(
    const float* __restrict__ external, const float* __restrict__ hx,
    const float* __restrict__ hE, const float* __restrict__ sc,
    const float* __restrict__ dist, const float* __restrict__ wbb,
    const float* __restrict__ wff, const float* __restrict__ wll,
    const float* __restrict__ theta, const float* __restrict__ part,
    float* __restrict__ vsnap) {
  const int wv = threadIdx.x >> 6;
  const int lane = threadIdx.x & 63;
  const int node = blockIdx.x * 2 + wv;   // this wave's node (setup + sim)

  __shared__ float Wall[2][3 * WSTR];   // per node: Wl | Wf | Wb (pre-scaled)
  __shared__ float hE_lds[2][DMAX];
  __shared__ float u_lds[2][STEPS * TRS];

  // --- global norm sums from ssq partials (one DPP reduce) ---
  float sb = part[lane], sf = part[64 + lane], sl = part[128 + lane];
  wave_reduce3(sb, sf, sl);
  const float inv_nb = 1.f / sqrtf(sb);
  const float inv_nf = 1.f / sqrtf(sf);
  const float inv_nl = 1.f / sqrtf(sl);

  // --- parameters ---
  const float VL = relu_(theta[0]), VI = relu_(theta[1]);
  const float VE = relu_(theta[2]), VNMDA = relu_(theta[3]);
  const float alpha_mg = relu_(theta[4]), VR = relu_(theta[5]);
  const float pi_sigma = relu_(theta[6]);
  const float gLp = relu_(theta[7]), Cc = relu_(theta[8]), kappa = relu_(theta[9]);
  const float g_gE = relu_(theta[10]), g_gE_sc = relu_(theta[11]);
  const float g_gI = relu_(theta[12]), g_gI_sc = relu_(theta[13]);
  const float g_gN = relu_(theta[14]), g_gN_sc = relu_(theta[15]);
  const float g_k = relu_(theta[16]);
  const float mu = 0.1f + relu_(theta[20]);
  const float uk = relu_(theta[21]) * theta[23];
  const float g_l = relu_(theta[24]), g_f = relu_(theta[25]), g_b = relu_(theta[26]);
  const float DTC = DT / Cc;
  const float dk = DT * kappa;
  const float nps = -pi_sigma, psVR = pi_sigma * VR;
  const float nam = -alpha_mg;

  const float dk1  = 1.f - dk;
  const float cA   = dk * g_l;     // folded into Wl bins
  const float cF   = dk * g_f;     // folded into Wf bins
  const float cB   = dk * g_b;     // folded into Wb bins
  const float cE0s = dk * g_gE;
  const float cE1e = dk * g_gE_sc;
  const float cE2e = dk * g_k;
  const float cI0  = dk * g_gI;
  const float cI1  = dk * g_gI_sc;
  const float cN0s = dk * g_gN;
  const float cN1  = dk * g_gN_sc;
  const float cN2  = dk * g_gN;
  const float gLVL = gLp * VL;
  const float L2E = 1.44269504088896f;
  const float npsL2 = nps * L2E;
  const float namL2 = nam * L2E;

  // --- stage LDS (wave w handles node w's slabs) ---
  for (int k = lane; k < 3 * WSTR; k += 64) Wall[wv][k] = 0.f;
  for (int d = lane; d < DMAX; d += 64) hE_lds[wv][d] = hE[node * DMAX + d];
  const float ukdk = dk * uk;
  for (int t = lane; t < STEPS * TRS; t += 64)
    u_lds[wv][t] = ukdk * external[node * STEPS * TRS + t];

  // --- bin weights by delay (pre-scaled), row sums, max delay ---
  const float scl = inv_nl * cA, scf = inv_nf * cF, scb = inv_nb * cB;
  float rl = 0.f, rf = 0.f, rb = 0.f;
  int mymax = 0;
#pragma unroll
  for (int kj = 0; kj < JPL; ++kj) {
    int j = lane + kj * 64;
    if (j < NODE) {
      int ij = node * NODE + j;
      int ji = j * NODE + node;
      float scij = sc[ij];
      float vb = expf(wbb[ij]) * scij * scb;
      float vf = expf(wff[ij]) * scij * scf;
      float vl = 0.5f * (expf(wll[ij]) * scij + expf(wll[ji]) * sc[ji]) * scl;
      int dd = (int)(dist[ij] / mu);
      dd = min(max(dd, 0), DMAX - 1);
      atomicAdd(&Wall[wv][dd], vl);
      atomicAdd(&Wall[wv][WSTR + dd], vf);
      atomicAdd(&Wall[wv][2 * WSTR + dd], vb);
      rl += vl; rf += vf; rb += vb;
      mymax = max(mymax, dd);
    }
  }
  wave_reduce3(rl, rf, rb);
  const int maxd = wave_max_int(mymax);   // per-wave (own node)

  if (maxd <= 126) {
    // ================= FAST PATH: per wave, pop-split over lane%3 ==========
    const int p3 = lane % 3;              // owned population (truth 0/1/2)
    const bool isP1 = (p3 == 1), isP2 = (p3 == 2), isP0 = (p3 == 0);

    const float cE0s2 = cE0s - rl;
    const float cN0s2 = cN0s - rl;
    const float cE1s = -rb;
    const float cE2s = -rf;
    // per-pop coefficient registers (VGPR by construction; pair with SGPRs)
    const float aE = isP1 ? cE1e : (isP2 ? cE2e : 0.f);
    const float bE = isP1 ? cE1s : (isP2 ? cE2s : cE0s2);
    const float uflag = isP1 ? 0.f : 1.f;
    const float cI = isP1 ? cI1 : cI0;
    const float pN = isP0 ? cN0s2 : 0.f;
    const float qN = isP1 ? cN1 : (isP2 ? cN2 : 0.f);
    const float fT1 = isP0 ? 1.f : 0.f;   // tE/tN selector flags
    const float fT2 = isP2 ? 1.f : 0.f;
    const float fT3 = isP1 ? 1.f : 0.f;
    float vngLVL = -gLVL;       PIN_V(vngLVL);
    float vpsVRL2 = psVR * L2E; PIN_V(vpsVRL2);
    // W0 bins: pinned to VGPR (they pair with SGPR bsP in the harvest)
    float vW0l = Wall[wv][0];        PIN_V(vW0l);
    float vW0f = Wall[wv][WSTR];     PIN_V(vW0f);
    float vW0b = Wall[wv][2 * WSTR]; PIN_V(vW0b);
    const float hE0 = hE_lds[wv][0];

    // own-pop state; EXACT pre-distortion (r8-proven) so the uniform body's
    // first E/I/N update with initial carries reproduces E(0),I(0),N(0).
    const float inv_dk1 = 1.f / dk1;
    const int hb = node * POP * 4 + 4 * p3;
    float V = hx[hb + 0];
    float E = (hx[hb + 1] - bE * hE0) * inv_dk1;
    float I = hx[hb + 2] * inv_dk1;
    float N = (hx[hb + 3] - pN * hE0) * inv_dk1;

    const bool wtop = (lane == 63);
    constexpr int NR = 2;                 // 64 lanes x 2 = 128 slots

    // shifted weights (deferred ring): Wsh[r] = W[2*lane + r + 1]
    float Wshl[NR], Wshf[NR], Wshb[NR];
#pragma unroll
    for (int r = 0; r < NR; ++r) {
      int s = NR * lane + r + 1;          // lane63,r1 -> W[128] = 0 (zeroed)
      Wshl[r] = Wall[wv][s];
      Wshf[r] = Wall[wv][WSTR + s];
      Wshb[r] = Wall[wv][2 * WSTR + s];
    }

    // prologue: P0[slot] = sum_{d>=slot} W[d]*hE[d-slot], slot = 2*lane+r
    float Ql[NR], Qf[NR], Qb[NR], hbuf[NR];
#pragma unroll
    for (int r = 0; r < NR; ++r) { Ql[r] = 0.f; Qf[r] = 0.f; Qb[r] = 0.f; hbuf[r] = 0.f; }
    for (int d = 0; d <= maxd; ++d) {
      float wl_ = Wall[wv][d], wf_ = Wall[wv][WSTR + d], wb_ = Wall[wv][2 * WSTR + d];
#pragma unroll
      for (int r = NR - 1; r > 0; --r) hbuf[r] = hbuf[r - 1];
      int idx = d - NR * lane;
      bool ok = idx >= 0;
      float hv = hE_lds[wv][ok ? idx : 0];
      hbuf[0] = ok ? hv : 0.f;
#pragma unroll
      for (int r = 0; r < NR; ++r) {
        Ql[r] = fmaf(wl_, hbuf[r], Ql[r]);
        Qf[r] = fmaf(wf_, hbuf[r], Qf[r]);
        Qb[r] = fmaf(wb_, hbuf[r], Qb[r]);
      }
    }
    // Q0 = P0 - W[slot]*hE0 (convert to deferred-scatter state)
#pragma unroll
    for (int r = 0; r < NR; ++r) {
      int s = NR * lane + r;
      Ql[r] = fmaf(-Wall[wv][s], hE0, Ql[r]);
      Qf[r] = fmaf(-Wall[wv][WSTR + s], hE0, Qf[r]);
      Qb[r] = fmaf(-Wall[wv][2 * WSTR + s], hE0, Qb[r]);
    }

    const float* uh = &u_lds[wv][0];
    // deferred carries (SGPR broadcasts produced at body t-1)
    float bsE = 0.f, bsI = 0.f, bsP = hE0;   // sigma(t-1); s(-1)=hE[0]
    float st1 = 0.f, st2 = 0.f, st3 = 0.f, carryU = 0.f;

    for (int tr = 0; tr < TRS; ++tr) {
      float uu[STEPS];
#pragma unroll
      for (int s2 = 0; s2 < STEPS; ++s2) uu[s2] = uh[s2 * TRS + tr];
#pragma unroll
      for (int st = 0; st < STEPS; ++st) {
        float Uprev = (st == 0) ? carryU : uu[st - 1];   // static select
        // [1] own-pop sigma(t), m(t) from V(t)
        float sg = rcp_(1.f + __builtin_amdgcn_exp2f(fmaf(npsL2, V, vpsVRL2)));
        float mm = rcp_(fmaf(0.2f, __builtin_amdgcn_exp2f(namL2 * V), 1.f));
        // [2] harvest a(t) = Q[0] + W0*s(t-1)  (truth on lane 0; pre-ring)
        float t1n = fmaf(vW0l, bsP, Ql[0]);
        float t2n = fmaf(vW0f, bsP, Qf[0]);
        float t3n = fmaf(vW0b, bsP, Qb[0]);
        // [3] next-body broadcasts: readlane -> SGPR (no LDS, low latency)
        float nbsE = rlane_(sg, 0);
        float nbsI = rlane_(sg, 1);
        float nbsP = rlane_(sg, 2);
        float nst1 = rlane_(t1n, 0);
        float nst2 = rlane_(t2n, 0);
        float nst3 = rlane_(t3n, 0);
        // [4] E/I/N <- step-t values using PREV-body carries (all <=1 SGPR)
        float g1 = fT1 * st1;
        float tE = fmaf(fT3, st3, fmaf(fT2, st2, g1));
        E = fmaf(dk1, E, fmaf(aE, bsE, fmaf(bE, bsP, fmaf(uflag, Uprev, tE))));
        I = fmaf(dk1, I, cI * bsI);
        N = fmaf(dk1, N, fmaf(pN, bsP, fmaf(qN, bsE, g1)));
        // [5] V <- V(t+1) using just-updated E/I/N(t), m(t)
        float Nm = N * mm;
        float R = fmaf(E, VE, fmaf(Nm, VNMDA, fmaf(I, -VI, vngLVL)));
        float S = ((gLp + E) + I) + Nm;
        V = fmaf(DTC, fmaf(-S, V, R), V);
        // [6] ring: Q(t)->Q(t+1), deferred scatter of s(t-1)=bsP (SGPR)
        float nll = wrol1(Ql[0]); nll = wtop ? 0.f : nll;
        float nlf = wrol1(Qf[0]); nlf = wtop ? 0.f : nlf;
        float nlb = wrol1(Qb[0]); nlb = wtop ? 0.f : nlb;
        Ql[0] = fmaf(Wshl[0], bsP, Ql[1]);
        Ql[1] = fmaf(Wshl[1], bsP, nll);
        Qf[0] = fmaf(Wshf[0], bsP, Qf[1]);
        Qf[1] = fmaf(Wshf[1], bsP, nlf);
        Qb[0] = fmaf(Wshb[0], bsP, Qb[1]);
        Qb[1] = fmaf(Wshb[1], bsP, nlb);
        // [7] commit deferred carries (renames in unrolled window)
        bsE = nbsE; bsI = nbsI; bsP = nbsP;
        st1 = nst1; st2 = nst2; st3 = nst3;
      }
      carryU = uu[STEPS - 1];
      if (lane == 2) vsnap[tr * NODE + node] = V;   // pop2 truth lane
    }
    return;
  }

  // ================= SLOW PATH (maxd>126): r3 core, wave w = node w ========
  {
    const float cE0s2 = cE0s - rl;
    const float cN0s2 = cN0s - rl;
    const float cE1s = -rb;
    const float cE2s = -rf;

    const int hb = node * POP * 4;
    float V0 = hx[hb + 0], V1 = hx[hb + 4], V2 = hx[hb + 8];
    float E0 = hx[hb + 1], E1 = hx[hb + 5], E2 = hx[hb + 9];
    float I0 = hx[hb + 2], I1 = hx[hb + 6], I2 = hx[hb + 10];
    float N0 = hx[hb + 3], N1 = hx[hb + 7], N2 = hx[hb + 11];

    const bool loS = (lane < 3);
    const float caL = loS ? npsL2 : namL2;
    const float cbL = loS ? psVR * L2E : 0.f;
    const float cdL = loS ? 1.f : 0.2f;
    const bool selB = (lane == 1) || (lane == 4);
    const bool selC = (lane == 2) || (lane == 5);
    const bool is63 = (lane == 63);

    float vE0s2 = cE0s2; PIN_V(vE0s2);
    float vN0s2 = cN0s2; PIN_V(vN0s2);
    float vE1e  = cE1e;  PIN_V(vE1e);
    float vE1s  = cE1s;  PIN_V(vE1s);
    float vE2e  = cE2e;  PIN_V(vE2e);
    float vE2s  = cE2s;  PIN_V(vE2s);
    float vI0   = cI0;   PIN_V(vI0);
    float vI1   = cI1;   PIN_V(vI1);
    float vN1   = cN1;   PIN_V(vN1);
    float vN2   = cN2;   PIN_V(vN2);
    float vngLVL = -gLVL; PIN_V(vngLVL);

    constexpr int NR = 8;
    float Wl[NR], Wf[NR], Wb[NR];
#pragma unroll
    for (int r = 0; r < NR; ++r) {
      int s = NR * lane + r;
      Wl[r] = Wall[wv][s];
      Wf[r] = Wall[wv][WSTR + s];
      Wb[r] = Wall[wv][2 * WSTR + s];
    }

    float Pl[NR], Pf[NR], Pb[NR], hbuf[NR];
#pragma unroll
    for (int r = 0; r < NR; ++r) { Pl[r] = 0.f; Pf[r] = 0.f; Pb[r] = 0.f; hbuf[r] = 0.f; }
    for (int d = 0; d <= maxd; ++d) {
      float wl_ = Wall[wv][d], wf_ = Wall[wv][WSTR + d], wb_ = Wall[wv][2 * WSTR + d];
#pragma unroll
      for (int r = NR - 1; r > 0; --r) hbuf[r] = hbuf[r - 1];
      int idx = d - NR * lane;
      bool ok = idx >= 0;
      float hv = hE_lds[wv][ok ? idx : 0];
      hbuf[0] = ok ? hv : 0.f;
#pragma unroll
      for (int r = 0; r < NR; ++r) {
        Pl[r] = fmaf(wl_, hbuf[r], Pl[r]);
        Pf[r] = fmaf(wf_, hbuf[r], Pf[r]);
        Pb[r] = fmaf(wb_, hbuf[r], Pb[r]);
      }
    }

    auto rotscat = [&](float* P, const float* W, float sPv) {
      float nl = is63 ? 0.f : wrol1(P[0]);
#pragma unroll
      for (int r = 0; r < NR - 1; ++r) P[r] = fmaf(W[r], sPv, P[r + 1]);
      P[NR - 1] = fmaf(W[NR - 1], sPv, nl);
    };

    for (int tr = 0; tr < TRS; ++tr) {
      float u_tr = (lane < STEPS) ? u_lds[wv][lane * TRS + tr] : 0.f;
#pragma unroll
      for (int st = 0; st < STEPS; ++st) {
        float t1 = bperm0_(Pl[0]);
        float t2 = bperm0_(Pf[0]);
        float t3 = bperm0_(Pb[0]);

        float Vs = selC ? V2 : (selB ? V1 : V0);
        float ex = __builtin_amdgcn_exp2f(fmaf(caL, Vs, cbL));
        float sg = rcp_(fmaf(cdL, ex, 1.f));
        float sE = rlane_(sg, 0), sI = rlane_(sg, 1), sP = rlane_(sg, 2);
        float m0 = rlane_(sg, 3), m1 = rlane_(sg, 4), m2 = rlane_(sg, 5);
        float U = rlane_(u_tr, st);

        float T0 = t1 + U;
        float T2 = t2 + U;
        float nE0 = fmaf(dk1, E0, fmaf(vE0s2, sP, T0));
        float nN0 = fmaf(dk1, N0, fmaf(vN0s2, sP, t1));
        float nE1 = fmaf(dk1, E1, fmaf(vE1e, sE, fmaf(vE1s, sP, t3)));
        float nN1 = fmaf(dk1, N1, vN1 * sE);
        float nE2 = fmaf(dk1, E2, fmaf(vE2e, sE, fmaf(vE2s, sP, T2)));
        float nN2 = fmaf(dk1, N2, vN2 * sE);
        float pI = vI0 * sI;
        float nI0 = fmaf(dk1, I0, pI);
        float nI1 = fmaf(dk1, I1, vI1 * sI);
        float nI2 = fmaf(dk1, I2, pI);

        float Nm0 = N0 * m0, Nm1 = N1 * m1, Nm2 = N2 * m2;
        float R0 = fmaf(E0, VE, fmaf(Nm0, VNMDA, fmaf(I0, -VI, vngLVL)));
        float R1 = fmaf(E1, VE, fmaf(Nm1, VNMDA, fmaf(I1, -VI, vngLVL)));
        float R2 = fmaf(E2, VE, fmaf(Nm2, VNMDA, fmaf(I2, -VI, vngLVL)));
        float S0 = gLp + E0 + I0 + Nm0;
        float S1 = gLp + E1 + I1 + Nm1;
        float S2 = gLp + E2 + I2 + Nm2;
        V0 = fmaf(DTC, fmaf(-S0, V0, R0), V0);
        V1 = fmaf(DTC, fmaf(-S1, V1, R1), V1);
        V2 = fmaf(DTC, fmaf(-S2, V2, R2), V2);
        E0 = nE0; E1 = nE1; E2 = nE2;
        I0 = nI0; I1 = nI1; I2 = nI2;
        N0 = nN0; N1 = nN1; N2 = nN2;

        rotscat(Pl, Wl, sP);
        rotscat(Pf, Wf, sP);
        rotscat(Pb, Wb, sP);
      }
      if (lane == 0) vsnap[tr * NODE + node] = V2;
    }
  }
}

// ---------------------------------------------------------------------------
// Kernel C: EEG readout. cm elimination: sum((lm-cm)@v) = a_o - mean_o(a_o).
// ---------------------------------------------------------------------------
__global__ __launch_bounds__(256) void eeg_kernel(
    const float* __restrict__ lm, const float* __restrict__ vsnap,
    const float* __restrict__ theta, float* __restrict__ out) {
  int tr = blockIdx.x;
  __shared__ float vs[NODE];
  __shared__ float partl[4][OUT];
  int tid = threadIdx.x;
  for (int n = tid; n < NODE; n += 256) vs[n] = vsnap[tr * NODE + n];
  __syncthreads();
  int o = tid & 63, w = tid >> 6;
  float acc = 0.f;
  for (int n = w * 100; n < w * 100 + 100; ++n)
    acc = fmaf(lm[o * NODE + n], vs[n], acc);
  partl[w][o] = acc;
  __syncthreads();
  if (tid < OUT) {
    float cy0 = theta[22], y0 = theta[19];
    float a = partl[0][tid] + partl[1][tid] + partl[2][tid] + partl[3][tid];
    float mean = wave_reduce1(a) * (1.f / OUT);
    out[tr * OUT + tid] = cy0 * (a - mean) - y0;
  }
}

extern "C" void kernel_launch(void* const* d_in, const int* in_sizes, int n_in,
                              void* d_out, int out_size, void* d_ws, size_t ws_size,
                              hipStream_t stream) {
  const float* external = (const float*)d_in[0];
  const float* hx       = (const float*)d_in[1];
  const float* hE       = (const float*)d_in[2];
  const float* sc       = (const float*)d_in[3];
  const float* dist     = (const float*)d_in[4];
  const float* wbb      = (const float*)d_in[5];
  const float* wff      = (const float*)d_in[6];
  const float* wll      = (const float*)d_in[7];
  const float* lm       = (const float*)d_in[8];
  const float* theta    = (const float*)d_in[9];
  float* out = (float*)d_out;

  float* vsnap = (float*)d_ws;               // TRS*NODE
  float* part  = vsnap + TRS * NODE;         // 3*64 ssq partials

  ssq_kernel<<<64, 256, 0, stream>>>(wbb, wff, wll, sc, part);
  sim_kernel<<<NODE / 2, 128, 0, stream>>>(external, hx, hE, sc, dist, wbb, wff,
                                           wll, theta, part, vsnap);
  eeg_kernel<<<TRS, 256, 0, stream>>>(lm, vsnap, theta, out);
}

// Round 10
// 137.244 us; speedup vs baseline: 3.2646x; 1.0003x over previous
//
#include <hip/hip_runtime.h>
#include <type_traits>

#define NODE 400
#define POP 3
#define TRS 40
#define STEPS 10
#define DMAX 500
#define OUT 64
#define DT 0.1f
#define JPL 7           // ceil(NODE/64) j-indices per lane
#define WSTR 512        // per-stream W bin stride (delta in [0,511])

__device__ __forceinline__ float relu_(float x) { return x > 0.f ? x : 0.f; }
__device__ __forceinline__ float rcp_(float x) { return __builtin_amdgcn_rcpf(x); }
__device__ __forceinline__ float rlane_(float v, int l) {
  return __builtin_bit_cast(float, __builtin_amdgcn_readlane(__builtin_bit_cast(int, v), l));
}
// broadcast lane 0 to all lanes, VGPR result (slow-path harvest)
__device__ __forceinline__ float bperm0_(float v) {
  return __builtin_bit_cast(float,
      __builtin_amdgcn_ds_bpermute(0, __builtin_bit_cast(int, v)));
}
// pin a value into a VGPR
#define PIN_V(x) asm volatile("" : "+v"(x))

// ---- DPP helpers
template <int CTRL>
__device__ __forceinline__ float dpp_mov(float x) {
  int r = __builtin_amdgcn_update_dpp(0, __builtin_bit_cast(int, x), CTRL,
                                      0xf, 0xf, true);
  return __builtin_bit_cast(float, r);
}
template <int CTRL>
__device__ __forceinline__ int dpp_movi(int x) {
  return __builtin_amdgcn_update_dpp(0, x, CTRL, 0xf, 0xf, true);
}
// wave rotate: dst[L] = src[(L+1) & 63]  (wave_rol:1 = 0x134, verified r1-r9)
__device__ __forceinline__ float wrol1(float x) { return dpp_mov<0x134>(x); }

__device__ __forceinline__ void wave_reduce3(float& a, float& b, float& c) {
  a += dpp_mov<0x111>(a); b += dpp_mov<0x111>(b); c += dpp_mov<0x111>(c);
  a += dpp_mov<0x112>(a); b += dpp_mov<0x112>(b); c += dpp_mov<0x112>(c);
  a += dpp_mov<0x114>(a); b += dpp_mov<0x114>(b); c += dpp_mov<0x114>(c);
  a += dpp_mov<0x118>(a); b += dpp_mov<0x118>(b); c += dpp_mov<0x118>(c);
  a += dpp_mov<0x142>(a); b += dpp_mov<0x142>(b); c += dpp_mov<0x142>(c);
  a += dpp_mov<0x143>(a); b += dpp_mov<0x143>(b); c += dpp_mov<0x143>(c);
  a = rlane_(a, 63); b = rlane_(b, 63); c = rlane_(c, 63);
}

__device__ __forceinline__ float wave_reduce1(float a) {
  a += dpp_mov<0x111>(a); a += dpp_mov<0x112>(a); a += dpp_mov<0x114>(a);
  a += dpp_mov<0x118>(a); a += dpp_mov<0x142>(a); a += dpp_mov<0x143>(a);
  return rlane_(a, 63);
}

__device__ __forceinline__ int wave_max_int(int x) {
  x = max(x, dpp_movi<0x111>(x));
  x = max(x, dpp_movi<0x112>(x));
  x = max(x, dpp_movi<0x114>(x));
  x = max(x, dpp_movi<0x118>(x));
  x = max(x, dpp_movi<0x142>(x));
  x = max(x, dpp_movi<0x143>(x));
  return __builtin_amdgcn_readlane(x, 63);
}

// ---------------------------------------------------------------------------
// Kernel A: Frobenius sum-of-squares partials (64 blocks, no atomics).
// ---------------------------------------------------------------------------
__global__ __launch_bounds__(256) void ssq_kernel(
    const float* __restrict__ wbb, const float* __restrict__ wff,
    const float* __restrict__ wll, const float* __restrict__ sc,
    float* __restrict__ part) {
  float eb = 0.f, ef = 0.f, el = 0.f;
  for (int idx = blockIdx.x * 256 + threadIdx.x; idx < NODE * NODE;
       idx += 64 * 256) {
    int i = idx / NODE, j = idx - i * NODE;
    int ji = j * NODE + i;
    float scij = sc[idx];
    float b = expf(wbb[idx]) * scij;
    float f = expf(wff[idx]) * scij;
    float l = 0.5f * (expf(wll[idx]) * scij + expf(wll[ji]) * sc[ji]);
    eb = fmaf(b, b, eb); ef = fmaf(f, f, ef); el = fmaf(l, l, el);
  }
  wave_reduce3(eb, ef, el);
  __shared__ float red[3][4];
  int lane = threadIdx.x & 63, wv = threadIdx.x >> 6;
  if (lane == 0) { red[0][wv] = eb; red[1][wv] = ef; red[2][wv] = el; }
  __syncthreads();
  if (threadIdx.x == 0) {
    part[blockIdx.x]       = red[0][0] + red[0][1] + red[0][2] + red[0][3];
    part[64 + blockIdx.x]  = red[1][0] + red[1][1] + red[1][2] + red[1][3];
    part[128 + blockIdx.x] = red[2][0] + red[2][1] + red[2][2] + red[2][3];
  }
}

// ---------------------------------------------------------------------------
// Kernel B fast path (r10): r9 structure, HAND-SCHEDULED body.
// r9's order put the 6 v_readlanes immediately after their producers (sg from
// rcp, t?n from harvest fmas) -> in-order issue stalled the full trans
// latency every step while independent E/I/N work waited below. New order:
// chain-start first, prev-carry consumers fill the trans shadow, ALL
// readlanes at body end (pinned by one sched_barrier so they can't be
// hoisted back toward their producers). Identical semantics.
// ---------------------------------------------------------------------------
__global__ __launch_bounds__(128) void sim_kernel(
    const float* __restrict__ external, const float* __restrict__ hx,
    const float* __restrict__ hE, const float* __restrict__ sc,
    const float* __restrict__ dist, const float* __restrict__ wbb,
    const float* __restrict__ wff, const float* __restrict__ wll,
    const float* __restrict__ theta, const float* __restrict__ part,
    float* __restrict__ vsnap) {
  const int wv = threadIdx.x >> 6;
  const int lane = threadIdx.x & 63;
  const int node = blockIdx.x * 2 + wv;   // this wave's node (setup + sim)

  __shared__ float Wall[2][3 * WSTR];   // per node: Wl | Wf | Wb (pre-scaled)
  __shared__ float hE_lds[2][DMAX];
  __shared__ float u_lds[2][STEPS * TRS];

  // --- global norm sums from ssq partials (one DPP reduce) ---
  float sb = part[lane], sf = part[64 + lane], sl = part[128 + lane];
  wave_reduce3(sb, sf, sl);
  const float inv_nb = 1.f / sqrtf(sb);
  const float inv_nf = 1.f / sqrtf(sf);
  const float inv_nl = 1.f / sqrtf(sl);

  // --- parameters ---
  const float VL = relu_(theta[0]), VI = relu_(theta[1]);
  const float VE = relu_(theta[2]), VNMDA = relu_(theta[3]);
  const float alpha_mg = relu_(theta[4]), VR = relu_(theta[5]);
  const float pi_sigma = relu_(theta[6]);
  const float gLp = relu_(theta[7]), Cc = relu_(theta[8]), kappa = relu_(theta[9]);
  const float g_gE = relu_(theta[10]), g_gE_sc = relu_(theta[11]);
  const float g_gI = relu_(theta[12]), g_gI_sc = relu_(theta[13]);
  const float g_gN = relu_(theta[14]), g_gN_sc = relu_(theta[15]);
  const float g_k = relu_(theta[16]);
  const float mu = 0.1f + relu_(theta[20]);
  const float uk = relu_(theta[21]) * theta[23];
  const float g_l = relu_(theta[24]), g_f = relu_(theta[25]), g_b = relu_(theta[26]);
  const float DTC = DT / Cc;
  const float dk = DT * kappa;
  const float nps = -pi_sigma, psVR = pi_sigma * VR;
  const float nam = -alpha_mg;

  const float dk1  = 1.f - dk;
  const float cA   = dk * g_l;     // folded into Wl bins
  const float cF   = dk * g_f;     // folded into Wf bins
  const float cB   = dk * g_b;     // folded into Wb bins
  const float cE0s = dk * g_gE;
  const float cE1e = dk * g_gE_sc;
  const float cE2e = dk * g_k;
  const float cI0  = dk * g_gI;
  const float cI1  = dk * g_gI_sc;
  const float cN0s = dk * g_gN;
  const float cN1  = dk * g_gN_sc;
  const float cN2  = dk * g_gN;
  const float gLVL = gLp * VL;
  const float L2E = 1.44269504088896f;
  const float npsL2 = nps * L2E;
  const float namL2 = nam * L2E;

  // --- stage LDS (wave w handles node w's slabs) ---
  for (int k = lane; k < 3 * WSTR; k += 64) Wall[wv][k] = 0.f;
  for (int d = lane; d < DMAX; d += 64) hE_lds[wv][d] = hE[node * DMAX + d];
  const float ukdk = dk * uk;
  for (int t = lane; t < STEPS * TRS; t += 64)
    u_lds[wv][t] = ukdk * external[node * STEPS * TRS + t];

  // --- bin weights by delay (pre-scaled), row sums, max delay ---
  const float scl = inv_nl * cA, scf = inv_nf * cF, scb = inv_nb * cB;
  float rl = 0.f, rf = 0.f, rb = 0.f;
  int mymax = 0;
#pragma unroll
  for (int kj = 0; kj < JPL; ++kj) {
    int j = lane + kj * 64;
    if (j < NODE) {
      int ij = node * NODE + j;
      int ji = j * NODE + node;
      float scij = sc[ij];
      float vb = expf(wbb[ij]) * scij * scb;
      float vf = expf(wff[ij]) * scij * scf;
      float vl = 0.5f * (expf(wll[ij]) * scij + expf(wll[ji]) * sc[ji]) * scl;
      int dd = (int)(dist[ij] / mu);
      dd = min(max(dd, 0), DMAX - 1);
      atomicAdd(&Wall[wv][dd], vl);
      atomicAdd(&Wall[wv][WSTR + dd], vf);
      atomicAdd(&Wall[wv][2 * WSTR + dd], vb);
      rl += vl; rf += vf; rb += vb;
      mymax = max(mymax, dd);
    }
  }
  wave_reduce3(rl, rf, rb);
  const int maxd = wave_max_int(mymax);   // per-wave (own node)

  if (maxd <= 126) {
    // ================= FAST PATH: per wave, pop-split over lane%3 ==========
    const int p3 = lane % 3;              // owned population (truth 0/1/2)
    const bool isP1 = (p3 == 1), isP2 = (p3 == 2), isP0 = (p3 == 0);

    const float cE0s2 = cE0s - rl;
    const float cN0s2 = cN0s - rl;
    const float cE1s = -rb;
    const float cE2s = -rf;
    // per-pop coefficient registers (VGPR by construction; pair with SGPRs)
    const float aE = isP1 ? cE1e : (isP2 ? cE2e : 0.f);
    const float bE = isP1 ? cE1s : (isP2 ? cE2s : cE0s2);
    const float uflag = isP1 ? 0.f : 1.f;
    const float cI = isP1 ? cI1 : cI0;
    const float pN = isP0 ? cN0s2 : 0.f;
    const float qN = isP1 ? cN1 : (isP2 ? cN2 : 0.f);
    const float fT1 = isP0 ? 1.f : 0.f;   // tE/tN selector flags
    const float fT2 = isP2 ? 1.f : 0.f;
    const float fT3 = isP1 ? 1.f : 0.f;
    float vngLVL = -gLVL;       PIN_V(vngLVL);
    float vpsVRL2 = psVR * L2E; PIN_V(vpsVRL2);
    // W0 bins: pinned to VGPR (they pair with SGPR bsP in the harvest)
    float vW0l = Wall[wv][0];        PIN_V(vW0l);
    float vW0f = Wall[wv][WSTR];     PIN_V(vW0f);
    float vW0b = Wall[wv][2 * WSTR]; PIN_V(vW0b);
    const float hE0 = hE_lds[wv][0];

    // own-pop state; EXACT pre-distortion (r8-proven) so the uniform body's
    // first E/I/N update with initial carries reproduces E(0),I(0),N(0).
    const float inv_dk1 = 1.f / dk1;
    const int hb = node * POP * 4 + 4 * p3;
    float V = hx[hb + 0];
    float E = (hx[hb + 1] - bE * hE0) * inv_dk1;
    float I = hx[hb + 2] * inv_dk1;
    float N = (hx[hb + 3] - pN * hE0) * inv_dk1;

    const bool wtop = (lane == 63);
    constexpr int NR = 2;                 // 64 lanes x 2 = 128 slots

    // shifted weights (deferred ring): Wsh[r] = W[2*lane + r + 1]
    float Wshl[NR], Wshf[NR], Wshb[NR];
#pragma unroll
    for (int r = 0; r < NR; ++r) {
      int s = NR * lane + r + 1;          // lane63,r1 -> W[128] = 0 (zeroed)
      Wshl[r] = Wall[wv][s];
      Wshf[r] = Wall[wv][WSTR + s];
      Wshb[r] = Wall[wv][2 * WSTR + s];
    }

    // prologue: P0[slot] = sum_{d>=slot} W[d]*hE[d-slot], slot = 2*lane+r
    float Ql[NR], Qf[NR], Qb[NR], hbuf[NR];
#pragma unroll
    for (int r = 0; r < NR; ++r) { Ql[r] = 0.f; Qf[r] = 0.f; Qb[r] = 0.f; hbuf[r] = 0.f; }
    for (int d = 0; d <= maxd; ++d) {
      float wl_ = Wall[wv][d], wf_ = Wall[wv][WSTR + d], wb_ = Wall[wv][2 * WSTR + d];
#pragma unroll
      for (int r = NR - 1; r > 0; --r) hbuf[r] = hbuf[r - 1];
      int idx = d - NR * lane;
      bool ok = idx >= 0;
      float hv = hE_lds[wv][ok ? idx : 0];
      hbuf[0] = ok ? hv : 0.f;
#pragma unroll
      for (int r = 0; r < NR; ++r) {
        Ql[r] = fmaf(wl_, hbuf[r], Ql[r]);
        Qf[r] = fmaf(wf_, hbuf[r], Qf[r]);
        Qb[r] = fmaf(wb_, hbuf[r], Qb[r]);
      }
    }
    // Q0 = P0 - W[slot]*hE0 (convert to deferred-scatter state)
#pragma unroll
    for (int r = 0; r < NR; ++r) {
      int s = NR * lane + r;
      Ql[r] = fmaf(-Wall[wv][s], hE0, Ql[r]);
      Qf[r] = fmaf(-Wall[wv][WSTR + s], hE0, Qf[r]);
      Qb[r] = fmaf(-Wall[wv][2 * WSTR + s], hE0, Qb[r]);
    }

    const float* uh = &u_lds[wv][0];
    // deferred carries (SGPR broadcasts produced at body t-1)
    float bsE = 0.f, bsI = 0.f, bsP = hE0;   // sigma(t-1); s(-1)=hE[0]
    float st1 = 0.f, st2 = 0.f, st3 = 0.f, carryU = 0.f;

    for (int tr = 0; tr < TRS; ++tr) {
      float uu[STEPS];
#pragma unroll
      for (int s2 = 0; s2 < STEPS; ++s2) uu[s2] = uh[s2 * TRS + tr];
#pragma unroll
      for (int st = 0; st < STEPS; ++st) {
        float Uprev = (st == 0) ? carryU : uu[st - 1];   // static select
        // [1] start the V-critical chain immediately (args + exp2)
        float a1 = fmaf(npsL2, V, vpsVRL2);
        float a2 = namL2 * V;
        float ex1 = __builtin_amdgcn_exp2f(a1);
        float ex2 = __builtin_amdgcn_exp2f(a2);
        // [2] E/I/N <- step-t values from PREV-body carries: fully
        //     independent of this body's trans -> fills the exp2 shadow
        float g1 = fT1 * st1;
        float tE = fmaf(fT3, st3, fmaf(fT2, st2, g1));
        E = fmaf(dk1, E, fmaf(aE, bsE, fmaf(bE, bsP, fmaf(uflag, Uprev, tE))));
        I = fmaf(dk1, I, cI * bsI);
        N = fmaf(dk1, N, fmaf(pN, bsP, fmaf(qN, bsE, g1)));
        // [3] harvest a(t) = Q[0] + W0*s(t-1) and ring-top reads (OLD Q)
        float t1n = fmaf(vW0l, bsP, Ql[0]);
        float t2n = fmaf(vW0f, bsP, Qf[0]);
        float t3n = fmaf(vW0b, bsP, Qb[0]);
        float nll = wrol1(Ql[0]); nll = wtop ? 0.f : nll;
        float nlf = wrol1(Qf[0]); nlf = wtop ? 0.f : nlf;
        float nlb = wrol1(Qb[0]); nlb = wtop ? 0.f : nlb;
        // [4] finish transcendentals
        float sg = rcp_(1.f + ex1);
        float mm = rcp_(fmaf(0.2f, ex2, 1.f));
        // [5] ring: Q(t)->Q(t+1), deferred scatter of s(t-1)=bsP (SGPR) —
        //     independent of sg/mm, fills the rcp shadow
        Ql[0] = fmaf(Wshl[0], bsP, Ql[1]);
        Ql[1] = fmaf(Wshl[1], bsP, nll);
        Qf[0] = fmaf(Wshf[0], bsP, Qf[1]);
        Qf[1] = fmaf(Wshf[1], bsP, nlf);
        Qb[0] = fmaf(Wshb[0], bsP, Qb[1]);
        Qb[1] = fmaf(Wshb[1], bsP, nlb);
        // [6] V <- V(t+1) using just-updated E/I/N(t), m(t)
        float Nm = N * mm;
        float R = fmaf(E, VE, fmaf(Nm, VNMDA, fmaf(I, -VI, vngLVL)));
        float S = ((gLp + E) + I) + Nm;
        V = fmaf(DTC, fmaf(-S, V, R), V);
        // [7] ALL readlanes at body end — producers are 15-25 instructions
        //     above, consumers are next body's [2]. Fence keeps them here.
        __builtin_amdgcn_sched_barrier(0);
        float nbsE = rlane_(sg, 0);
        float nbsI = rlane_(sg, 1);
        float nbsP = rlane_(sg, 2);
        float nst1 = rlane_(t1n, 0);
        float nst2 = rlane_(t2n, 0);
        float nst3 = rlane_(t3n, 0);
        // [8] commit deferred carries (renames in unrolled window)
        bsE = nbsE; bsI = nbsI; bsP = nbsP;
        st1 = nst1; st2 = nst2; st3 = nst3;
      }
      carryU = uu[STEPS - 1];
      if (lane == 2) vsnap[tr * NODE + node] = V;   // pop2 truth lane
    }
    return;
  }

  // ================= SLOW PATH (maxd>126): r3 core, wave w = node w ========
  {
    const float cE0s2 = cE0s - rl;
    const float cN0s2 = cN0s - rl;
    const float cE1s = -rb;
    const float cE2s = -rf;

    const int hb = node * POP * 4;
    float V0 = hx[hb + 0], V1 = hx[hb + 4], V2 = hx[hb + 8];
    float E0 = hx[hb + 1], E1 = hx[hb + 5], E2 = hx[hb + 9];
    float I0 = hx[hb + 2], I1 = hx[hb + 6], I2 = hx[hb + 10];
    float N0 = hx[hb + 3], N1 = hx[hb + 7], N2 = hx[hb + 11];

    const bool loS = (lane < 3);
    const float caL = loS ? npsL2 : namL2;
    const float cbL = loS ? psVR * L2E : 0.f;
    const float cdL = loS ? 1.f : 0.2f;
    const bool selB = (lane == 1) || (lane == 4);
    const bool selC = (lane == 2) || (lane == 5);
    const bool is63 = (lane == 63);

    float vE0s2 = cE0s2; PIN_V(vE0s2);
    float vN0s2 = cN0s2; PIN_V(vN0s2);
    float vE1e  = cE1e;  PIN_V(vE1e);
    float vE1s  = cE1s;  PIN_V(vE1s);
    float vE2e  = cE2e;  PIN_V(vE2e);
    float vE2s  = cE2s;  PIN_V(vE2s);
    float vI0   = cI0;   PIN_V(vI0);
    float vI1   = cI1;   PIN_V(vI1);
    float vN1   = cN1;   PIN_V(vN1);
    float vN2   = cN2;   PIN_V(vN2);
    float vngLVL = -gLVL; PIN_V(vngLVL);

    constexpr int NR = 8;
    float Wl[NR], Wf[NR], Wb[NR];
#pragma unroll
    for (int r = 0; r < NR; ++r) {
      int s = NR * lane + r;
      Wl[r] = Wall[wv][s];
      Wf[r] = Wall[wv][WSTR + s];
      Wb[r] = Wall[wv][2 * WSTR + s];
    }

    float Pl[NR], Pf[NR], Pb[NR], hbuf[NR];
#pragma unroll
    for (int r = 0; r < NR; ++r) { Pl[r] = 0.f; Pf[r] = 0.f; Pb[r] = 0.f; hbuf[r] = 0.f; }
    for (int d = 0; d <= maxd; ++d) {
      float wl_ = Wall[wv][d], wf_ = Wall[wv][WSTR + d], wb_ = Wall[wv][2 * WSTR + d];
#pragma unroll
      for (int r = NR - 1; r > 0; --r) hbuf[r] = hbuf[r - 1];
      int idx = d - NR * lane;
      bool ok = idx >= 0;
      float hv = hE_lds[wv][ok ? idx : 0];
      hbuf[0] = ok ? hv : 0.f;
#pragma unroll
      for (int r = 0; r < NR; ++r) {
        Pl[r] = fmaf(wl_, hbuf[r], Pl[r]);
        Pf[r] = fmaf(wf_, hbuf[r], Pf[r]);
        Pb[r] = fmaf(wb_, hbuf[r], Pb[r]);
      }
    }

    auto rotscat = [&](float* P, const float* W, float sPv) {
      float nl = is63 ? 0.f : wrol1(P[0]);
#pragma unroll
      for (int r = 0; r < NR - 1; ++r) P[r] = fmaf(W[r], sPv, P[r + 1]);
      P[NR - 1] = fmaf(W[NR - 1], sPv, nl);
    };

    for (int tr = 0; tr < TRS; ++tr) {
      float u_tr = (lane < STEPS) ? u_lds[wv][lane * TRS + tr] : 0.f;
#pragma unroll
      for (int st = 0; st < STEPS; ++st) {
        float t1 = bperm0_(Pl[0]);
        float t2 = bperm0_(Pf[0]);
        float t3 = bperm0_(Pb[0]);

        float Vs = selC ? V2 : (selB ? V1 : V0);
        float ex = __builtin_amdgcn_exp2f(fmaf(caL, Vs, cbL));
        float sg = rcp_(fmaf(cdL, ex, 1.f));
        float sE = rlane_(sg, 0), sI = rlane_(sg, 1), sP = rlane_(sg, 2);
        float m0 = rlane_(sg, 3), m1 = rlane_(sg, 4), m2 = rlane_(sg, 5);
        float U = rlane_(u_tr, st);

        float T0 = t1 + U;
        float T2 = t2 + U;
        float nE0 = fmaf(dk1, E0, fmaf(vE0s2, sP, T0));
        float nN0 = fmaf(dk1, N0, fmaf(vN0s2, sP, t1));
        float nE1 = fmaf(dk1, E1, fmaf(vE1e, sE, fmaf(vE1s, sP, t3)));
        float nN1 = fmaf(dk1, N1, vN1 * sE);
        float nE2 = fmaf(dk1, E2, fmaf(vE2e, sE, fmaf(vE2s, sP, T2)));
        float nN2 = fmaf(dk1, N2, vN2 * sE);
        float pI = vI0 * sI;
        float nI0 = fmaf(dk1, I0, pI);
        float nI1 = fmaf(dk1, I1, vI1 * sI);
        float nI2 = fmaf(dk1, I2, pI);

        float Nm0 = N0 * m0, Nm1 = N1 * m1, Nm2 = N2 * m2;
        float R0 = fmaf(E0, VE, fmaf(Nm0, VNMDA, fmaf(I0, -VI, vngLVL)));
        float R1 = fmaf(E1, VE, fmaf(Nm1, VNMDA, fmaf(I1, -VI, vngLVL)));
        float R2 = fmaf(E2, VE, fmaf(Nm2, VNMDA, fmaf(I2, -VI, vngLVL)));
        float S0 = gLp + E0 + I0 + Nm0;
        float S1 = gLp + E1 + I1 + Nm1;
        float S2 = gLp + E2 + I2 + Nm2;
        V0 = fmaf(DTC, fmaf(-S0, V0, R0), V0);
        V1 = fmaf(DTC, fmaf(-S1, V1, R1), V1);
        V2 = fmaf(DTC, fmaf(-S2, V2, R2), V2);
        E0 = nE0; E1 = nE1; E2 = nE2;
        I0 = nI0; I1 = nI1; I2 = nI2;
        N0 = nN0; N1 = nN1; N2 = nN2;

        rotscat(Pl, Wl, sP);
        rotscat(Pf, Wf, sP);
        rotscat(Pb, Wb, sP);
      }
      if (lane == 0) vsnap[tr * NODE + node] = V2;
    }
  }
}

// ---------------------------------------------------------------------------
// Kernel C: EEG readout. cm elimination: sum((lm-cm)@v) = a_o - mean_o(a_o).
// ---------------------------------------------------------------------------
__global__ __launch_bounds__(256) void eeg_kernel(
    const float* __restrict__ lm, const float* __restrict__ vsnap,
    const float* __restrict__ theta, float* __restrict__ out) {
  int tr = blockIdx.x;
  __shared__ float vs[NODE];
  __shared__ float partl[4][OUT];
  int tid = threadIdx.x;
  for (int n = tid; n < NODE; n += 256) vs[n] = vsnap[tr * NODE + n];
  __syncthreads();
  int o = tid & 63, w = tid >> 6;
  float acc = 0.f;
  for (int n = w * 100; n < w * 100 + 100; ++n)
    acc = fmaf(lm[o * NODE + n], vs[n], acc);
  partl[w][o] = acc;
  __syncthreads();
  if (tid < OUT) {
    float cy0 = theta[22], y0 = theta[19];
    float a = partl[0][tid] + partl[1][tid] + partl[2][tid] + partl[3][tid];
    float mean = wave_reduce1(a) * (1.f / OUT);
    out[tr * OUT + tid] = cy0 * (a - mean) - y0;
  }
}

extern "C" void kernel_launch(void* const* d_in, const int* in_sizes, int n_in,
                              void* d_out, int out_size, void* d_ws, size_t ws_size,
                              hipStream_t stream) {
  const float* external = (const float*)d_in[0];
  const float* hx       = (const float*)d_in[1];
  const float* hE       = (const float*)d_in[2];
  const float* sc       = (const float*)d_in[3];
  const float* dist     = (const float*)d_in[4];
  const float* wbb      = (const float*)d_in[5];
  const float* wff      = (const float*)d_in[6];
  const float* wll      = (const float*)d_in[7];
  const float* lm       = (const float*)d_in[8];
  const float* theta    = (const float*)d_in[9];
  float* out = (float*)d_out;

  float* vsnap = (float*)d_ws;               // TRS*NODE
  float* part  = vsnap + TRS * NODE;         // 3*64 ssq partials

  ssq_kernel<<<64, 256, 0, stream>>>(wbb, wff, wll, sc, part);
  sim_kernel<<<NODE / 2, 128, 0, stream>>>(external, hx, hE, sc, dist, wbb, wff,
                                           wll, theta, part, vsnap);
  eeg_kernel<<<TRS, 256, 0, stream>>>(lm, vsnap, theta, out);
}

// Round 11
// 135.409 us; speedup vs baseline: 3.3088x; 1.0135x over previous
//
#include <hip/hip_runtime.h>
#include <type_traits>

#define NODE 400
#define POP 3
#define TRS 40
#define STEPS 10
#define DMAX 500
#define OUT 64
#define DT 0.1f
#define JPL 7           // ceil(NODE/64) j-indices per lane
#define WSTR 512        // per-stream W bin stride (delta in [0,511])

typedef float f32x2 __attribute__((ext_vector_type(2)));

__device__ __forceinline__ float relu_(float x) { return x > 0.f ? x : 0.f; }
__device__ __forceinline__ float rcp_(float x) { return __builtin_amdgcn_rcpf(x); }
__device__ __forceinline__ float rlane_(float v, int l) {
  return __builtin_bit_cast(float, __builtin_amdgcn_readlane(__builtin_bit_cast(int, v), l));
}
// broadcast lane 0 to all lanes, VGPR result (slow-path harvest)
__device__ __forceinline__ float bperm0_(float v) {
  return __builtin_bit_cast(float,
      __builtin_amdgcn_ds_bpermute(0, __builtin_bit_cast(int, v)));
}
// pin a value into a VGPR
#define PIN_V(x) asm volatile("" : "+v"(x))

// ---- DPP helpers
template <int CTRL>
__device__ __forceinline__ float dpp_mov(float x) {
  int r = __builtin_amdgcn_update_dpp(0, __builtin_bit_cast(int, x), CTRL,
                                      0xf, 0xf, true);
  return __builtin_bit_cast(float, r);
}
template <int CTRL>
__device__ __forceinline__ int dpp_movi(int x) {
  return __builtin_amdgcn_update_dpp(0, x, CTRL, 0xf, 0xf, true);
}
// wave rotate: dst[L] = src[(L+1) & 63]  (wave_rol:1 = 0x134, verified r1-r10)
__device__ __forceinline__ float wrol1(float x) { return dpp_mov<0x134>(x); }

__device__ __forceinline__ void wave_reduce3(float& a, float& b, float& c) {
  a += dpp_mov<0x111>(a); b += dpp_mov<0x111>(b); c += dpp_mov<0x111>(c);
  a += dpp_mov<0x112>(a); b += dpp_mov<0x112>(b); c += dpp_mov<0x112>(c);
  a += dpp_mov<0x114>(a); b += dpp_mov<0x114>(b); c += dpp_mov<0x114>(c);
  a += dpp_mov<0x118>(a); b += dpp_mov<0x118>(b); c += dpp_mov<0x118>(c);
  a += dpp_mov<0x142>(a); b += dpp_mov<0x142>(b); c += dpp_mov<0x142>(c);
  a += dpp_mov<0x143>(a); b += dpp_mov<0x143>(b); c += dpp_mov<0x143>(c);
  a = rlane_(a, 63); b = rlane_(b, 63); c = rlane_(c, 63);
}

__device__ __forceinline__ float wave_reduce1(float a) {
  a += dpp_mov<0x111>(a); a += dpp_mov<0x112>(a); a += dpp_mov<0x114>(a);
  a += dpp_mov<0x118>(a); a += dpp_mov<0x142>(a); a += dpp_mov<0x143>(a);
  return rlane_(a, 63);
}

__device__ __forceinline__ int wave_max_int(int x) {
  x = max(x, dpp_movi<0x111>(x));
  x = max(x, dpp_movi<0x112>(x));
  x = max(x, dpp_movi<0x114>(x));
  x = max(x, dpp_movi<0x118>(x));
  x = max(x, dpp_movi<0x142>(x));
  x = max(x, dpp_movi<0x143>(x));
  return __builtin_amdgcn_readlane(x, 63);
}

// ---------------------------------------------------------------------------
// Kernel A: Frobenius sum-of-squares partials (64 blocks, no atomics).
// ---------------------------------------------------------------------------
__global__ __launch_bounds__(256) void ssq_kernel(
    const float* __restrict__ wbb, const float* __restrict__ wff,
    const float* __restrict__ wll, const float* __restrict__ sc,
    float* __restrict__ part) {
  float eb = 0.f, ef = 0.f, el = 0.f;
  for (int idx = blockIdx.x * 256 + threadIdx.x; idx < NODE * NODE;
       idx += 64 * 256) {
    int i = idx / NODE, j = idx - i * NODE;
    int ji = j * NODE + i;
    float scij = sc[idx];
    float b = expf(wbb[idx]) * scij;
    float f = expf(wff[idx]) * scij;
    float l = 0.5f * (expf(wll[idx]) * scij + expf(wll[ji]) * sc[ji]);
    eb = fmaf(b, b, eb); ef = fmaf(f, f, ef); el = fmaf(l, l, el);
  }
  wave_reduce3(eb, ef, el);
  __shared__ float red[3][4];
  int lane = threadIdx.x & 63, wv = threadIdx.x >> 6;
  if (lane == 0) { red[0][wv] = eb; red[1][wv] = ef; red[2][wv] = el; }
  __syncthreads();
  if (threadIdx.x == 0) {
    part[blockIdx.x]       = red[0][0] + red[0][1] + red[0][2] + red[0][3];
    part[64 + blockIdx.x]  = red[1][0] + red[1][1] + red[1][2] + red[1][3];
    part[128 + blockIdx.x] = red[2][0] + red[2][1] + red[2][2] + red[2][3];
  }
}

// ---------------------------------------------------------------------------
// Kernel B fast path (r11): r10 structure + PACKED FP32 (v_pk_fma_f32).
// Pairs: (l,f) ring streams (same bsP multiplicand) -> ring 4 fma -> 2 pk,
// harvest (t1,t2) -> 1 pk; (E,N) share the fma(dk1,X,inner) form -> 1 pk.
// Expressed as float2 + __builtin_elementwise_fma (falls back to scalar fma
// if unpacked -> no regression risk). All semantics identical to r10.
// ---------------------------------------------------------------------------
__global__ __launch_bounds__(128) void sim_kernel(
    const float* __restrict__ external, const float* __restrict__ hx,
    const float* __restrict__ hE, const float* __restrict__ sc,
    const float* __restrict__ dist, const float* __restrict__ wbb,
    const float* __restrict__ wff, const float* __restrict__ wll,
    const float* __restrict__ theta, const float* __restrict__ part,
    float* __restrict__ vsnap) {
  const int wv = threadIdx.x >> 6;
  const int lane = threadIdx.x & 63;
  const int node = blockIdx.x * 2 + wv;   // this wave's node (setup + sim)

  __shared__ float Wall[2][3 * WSTR];   // per node: Wl | Wf | Wb (pre-scaled)
  __shared__ float hE_lds[2][DMAX];
  __shared__ float u_lds[2][STEPS * TRS];

  // --- global norm sums from ssq partials (one DPP reduce) ---
  float sb = part[lane], sf = part[64 + lane], sl = part[128 + lane];
  wave_reduce3(sb, sf, sl);
  const float inv_nb = 1.f / sqrtf(sb);
  const float inv_nf = 1.f / sqrtf(sf);
  const float inv_nl = 1.f / sqrtf(sl);

  // --- parameters ---
  const float VL = relu_(theta[0]), VI = relu_(theta[1]);
  const float VE = relu_(theta[2]), VNMDA = relu_(theta[3]);
  const float alpha_mg = relu_(theta[4]), VR = relu_(theta[5]);
  const float pi_sigma = relu_(theta[6]);
  const float gLp = relu_(theta[7]), Cc = relu_(theta[8]), kappa = relu_(theta[9]);
  const float g_gE = relu_(theta[10]), g_gE_sc = relu_(theta[11]);
  const float g_gI = relu_(theta[12]), g_gI_sc = relu_(theta[13]);
  const float g_gN = relu_(theta[14]), g_gN_sc = relu_(theta[15]);
  const float g_k = relu_(theta[16]);
  const float mu = 0.1f + relu_(theta[20]);
  const float uk = relu_(theta[21]) * theta[23];
  const float g_l = relu_(theta[24]), g_f = relu_(theta[25]), g_b = relu_(theta[26]);
  const float DTC = DT / Cc;
  const float dk = DT * kappa;
  const float nps = -pi_sigma, psVR = pi_sigma * VR;
  const float nam = -alpha_mg;

  const float dk1  = 1.f - dk;
  const float cA   = dk * g_l;     // folded into Wl bins
  const float cF   = dk * g_f;     // folded into Wf bins
  const float cB   = dk * g_b;     // folded into Wb bins
  const float cE0s = dk * g_gE;
  const float cE1e = dk * g_gE_sc;
  const float cE2e = dk * g_k;
  const float cI0  = dk * g_gI;
  const float cI1  = dk * g_gI_sc;
  const float cN0s = dk * g_gN;
  const float cN1  = dk * g_gN_sc;
  const float cN2  = dk * g_gN;
  const float gLVL = gLp * VL;
  const float L2E = 1.44269504088896f;
  const float npsL2 = nps * L2E;
  const float namL2 = nam * L2E;

  // --- stage LDS (wave w handles node w's slabs) ---
  for (int k = lane; k < 3 * WSTR; k += 64) Wall[wv][k] = 0.f;
  for (int d = lane; d < DMAX; d += 64) hE_lds[wv][d] = hE[node * DMAX + d];
  const float ukdk = dk * uk;
  for (int t = lane; t < STEPS * TRS; t += 64)
    u_lds[wv][t] = ukdk * external[node * STEPS * TRS + t];

  // --- bin weights by delay (pre-scaled), row sums, max delay ---
  const float scl = inv_nl * cA, scf = inv_nf * cF, scb = inv_nb * cB;
  float rl = 0.f, rf = 0.f, rb = 0.f;
  int mymax = 0;
#pragma unroll
  for (int kj = 0; kj < JPL; ++kj) {
    int j = lane + kj * 64;
    if (j < NODE) {
      int ij = node * NODE + j;
      int ji = j * NODE + node;
      float scij = sc[ij];
      float vb = expf(wbb[ij]) * scij * scb;
      float vf = expf(wff[ij]) * scij * scf;
      float vl = 0.5f * (expf(wll[ij]) * scij + expf(wll[ji]) * sc[ji]) * scl;
      int dd = (int)(dist[ij] / mu);
      dd = min(max(dd, 0), DMAX - 1);
      atomicAdd(&Wall[wv][dd], vl);
      atomicAdd(&Wall[wv][WSTR + dd], vf);
      atomicAdd(&Wall[wv][2 * WSTR + dd], vb);
      rl += vl; rf += vf; rb += vb;
      mymax = max(mymax, dd);
    }
  }
  wave_reduce3(rl, rf, rb);
  const int maxd = wave_max_int(mymax);   // per-wave (own node)

  if (maxd <= 126) {
    // ================= FAST PATH: per wave, pop-split over lane%3 ==========
    const int p3 = lane % 3;              // owned population (truth 0/1/2)
    const bool isP1 = (p3 == 1), isP2 = (p3 == 2), isP0 = (p3 == 0);

    const float cE0s2 = cE0s - rl;
    const float cN0s2 = cN0s - rl;
    const float cE1s = -rb;
    const float cE2s = -rf;
    // per-pop coefficient registers (VGPR by construction; pair with SGPRs)
    const float aE = isP1 ? cE1e : (isP2 ? cE2e : 0.f);
    const float bE = isP1 ? cE1s : (isP2 ? cE2s : cE0s2);
    const float uflag = isP1 ? 0.f : 1.f;
    const float cI = isP1 ? cI1 : cI0;
    const float pN = isP0 ? cN0s2 : 0.f;
    const float qN = isP1 ? cN1 : (isP2 ? cN2 : 0.f);
    const float fT1 = isP0 ? 1.f : 0.f;   // tE/tN selector flags
    const float fT2 = isP2 ? 1.f : 0.f;
    const float fT3 = isP1 ? 1.f : 0.f;
    float vngLVL = -gLVL;       PIN_V(vngLVL);
    float vpsVRL2 = psVR * L2E; PIN_V(vpsVRL2);
    // W0 bins: pinned to VGPR (they pair with SGPR bsP in the harvest)
    float vW0l = Wall[wv][0];        PIN_V(vW0l);
    float vW0f = Wall[wv][WSTR];     PIN_V(vW0f);
    float vW0b = Wall[wv][2 * WSTR]; PIN_V(vW0b);
    const float hE0 = hE_lds[wv][0];

    // own-pop state; EXACT pre-distortion (r8-proven) so the uniform body's
    // first E/I/N update with initial carries reproduces E(0),I(0),N(0).
    const float inv_dk1 = 1.f / dk1;
    const int hb = node * POP * 4 + 4 * p3;
    float V = hx[hb + 0];
    f32x2 EN = {(hx[hb + 1] - bE * hE0) * inv_dk1,
                (hx[hb + 3] - pN * hE0) * inv_dk1};
    float I = hx[hb + 2] * inv_dk1;

    const bool wtop = (lane == 63);
    constexpr int NR = 2;                 // 64 lanes x 2 = 128 slots

    // shifted weights (deferred ring): Wsh[r] = W[2*lane + r + 1]
    float Wshl[NR], Wshf[NR], Wshb[NR];
#pragma unroll
    for (int r = 0; r < NR; ++r) {
      int s = NR * lane + r + 1;          // lane63,r1 -> W[128] = 0 (zeroed)
      Wshl[r] = Wall[wv][s];
      Wshf[r] = Wall[wv][WSTR + s];
      Wshb[r] = Wall[wv][2 * WSTR + s];
    }

    // prologue: P0[slot] = sum_{d>=slot} W[d]*hE[d-slot], slot = 2*lane+r
    float Ql[NR], Qf[NR], Qb[NR], hbuf[NR];
#pragma unroll
    for (int r = 0; r < NR; ++r) { Ql[r] = 0.f; Qf[r] = 0.f; Qb[r] = 0.f; hbuf[r] = 0.f; }
    for (int d = 0; d <= maxd; ++d) {
      float wl_ = Wall[wv][d], wf_ = Wall[wv][WSTR + d], wb_ = Wall[wv][2 * WSTR + d];
#pragma unroll
      for (int r = NR - 1; r > 0; --r) hbuf[r] = hbuf[r - 1];
      int idx = d - NR * lane;
      bool ok = idx >= 0;
      float hv = hE_lds[wv][ok ? idx : 0];
      hbuf[0] = ok ? hv : 0.f;
#pragma unroll
      for (int r = 0; r < NR; ++r) {
        Ql[r] = fmaf(wl_, hbuf[r], Ql[r]);
        Qf[r] = fmaf(wf_, hbuf[r], Qf[r]);
        Qb[r] = fmaf(wb_, hbuf[r], Qb[r]);
      }
    }
    // Q0 = P0 - W[slot]*hE0 (convert to deferred-scatter state)
#pragma unroll
    for (int r = 0; r < NR; ++r) {
      int s = NR * lane + r;
      Ql[r] = fmaf(-Wall[wv][s], hE0, Ql[r]);
      Qf[r] = fmaf(-Wall[wv][WSTR + s], hE0, Qf[r]);
      Qb[r] = fmaf(-Wall[wv][2 * WSTR + s], hE0, Qb[r]);
    }

    // --- pack the (l,f) streams into pairs for v_pk_fma_f32 ---
    f32x2 Qlf0 = {Ql[0], Qf[0]};
    f32x2 Qlf1 = {Ql[1], Qf[1]};
    f32x2 Wlf0 = {Wshl[0], Wshf[0]};
    f32x2 Wlf1 = {Wshl[1], Wshf[1]};
    f32x2 vW0lf = {vW0l, vW0f};
    f32x2 dk12 = {dk1, dk1};
    float Qb0 = Qb[0], Qb1 = Qb[1];
    const float Wb0s = Wshb[0], Wb1s = Wshb[1];

    const float* uh = &u_lds[wv][0];
    // deferred carries (SGPR broadcasts produced at body t-1)
    float bsE = 0.f, bsI = 0.f, bsP = hE0;   // sigma(t-1); s(-1)=hE[0]
    float st1 = 0.f, st2 = 0.f, st3 = 0.f, carryU = 0.f;

    for (int tr = 0; tr < TRS; ++tr) {
      float uu[STEPS];
#pragma unroll
      for (int s2 = 0; s2 < STEPS; ++s2) uu[s2] = uh[s2 * TRS + tr];
#pragma unroll
      for (int st = 0; st < STEPS; ++st) {
        float Uprev = (st == 0) ? carryU : uu[st - 1];   // static select
        // [1] start the V-critical chain immediately (args + exp2)
        float a1 = fmaf(npsL2, V, vpsVRL2);
        float a2 = namL2 * V;
        float ex1 = __builtin_amdgcn_exp2f(a1);
        float ex2 = __builtin_amdgcn_exp2f(a2);
        // [2] E/I/N <- step-t values from PREV-body carries (fills exp2
        //     shadow). (E,N) outer packed.
        float g1 = fT1 * st1;
        float tE = fmaf(fT3, st3, fmaf(fT2, st2, g1));
        float e1 = fmaf(uflag, Uprev, tE);
        float e2 = fmaf(bE, bsP, e1);
        float innerE = fmaf(aE, bsE, e2);
        float innerN = fmaf(pN, bsP, fmaf(qN, bsE, g1));
        f32x2 innerEN = {innerE, innerN};
        EN = __builtin_elementwise_fma(dk12, EN, innerEN);
        I = fmaf(dk1, I, cI * bsI);
        // [3] harvest a(t) = Q[0] + W0*s(t-1) (l,f packed) + ring-top reads
        f32x2 bsP2 = {bsP, bsP};
        f32x2 tlf = __builtin_elementwise_fma(vW0lf, bsP2, Qlf0);
        float t3n = fmaf(vW0b, bsP, Qb0);
        float nll = wrol1(Qlf0.x); nll = wtop ? 0.f : nll;
        float nlf = wrol1(Qlf0.y); nlf = wtop ? 0.f : nlf;
        float nlb = wrol1(Qb0);    nlb = wtop ? 0.f : nlb;
        // [4] finish transcendentals
        float sg = rcp_(1.f + ex1);
        float mm = rcp_(fmaf(0.2f, ex2, 1.f));
        // [5] ring: Q(t)->Q(t+1), deferred scatter of s(t-1)=bsP; (l,f)
        //     packed (2 pk), b scalar (2 fma)
        Qlf0 = __builtin_elementwise_fma(Wlf0, bsP2, Qlf1);
        f32x2 nlp = {nll, nlf};
        Qlf1 = __builtin_elementwise_fma(Wlf1, bsP2, nlp);
        Qb0 = fmaf(Wb0s, bsP, Qb1);
        Qb1 = fmaf(Wb1s, bsP, nlb);
        // [6] V <- V(t+1) using just-updated E/I/N(t), m(t)
        float Nm = EN.y * mm;
        float R = fmaf(EN.x, VE, fmaf(Nm, VNMDA, fmaf(I, -VI, vngLVL)));
        float S = ((gLp + EN.x) + I) + Nm;
        V = fmaf(DTC, fmaf(-S, V, R), V);
        // [7] readlanes at body end (producers far above, consumers next
        //     body). Fence keeps them here.
        __builtin_amdgcn_sched_barrier(0);
        float nbsE = rlane_(sg, 0);
        float nbsI = rlane_(sg, 1);
        float nbsP = rlane_(sg, 2);
        float nst1 = rlane_(tlf.x, 0);
        float nst2 = rlane_(tlf.y, 0);
        float nst3 = rlane_(t3n, 0);
        // [8] commit deferred carries (renames in unrolled window)
        bsE = nbsE; bsI = nbsI; bsP = nbsP;
        st1 = nst1; st2 = nst2; st3 = nst3;
      }
      carryU = uu[STEPS - 1];
      if (lane == 2) vsnap[tr * NODE + node] = V;   // pop2 truth lane
    }
    return;
  }

  // ================= SLOW PATH (maxd>126): r3 core, wave w = node w ========
  {
    const float cE0s2 = cE0s - rl;
    const float cN0s2 = cN0s - rl;
    const float cE1s = -rb;
    const float cE2s = -rf;

    const int hb = node * POP * 4;
    float V0 = hx[hb + 0], V1 = hx[hb + 4], V2 = hx[hb + 8];
    float E0 = hx[hb + 1], E1 = hx[hb + 5], E2 = hx[hb + 9];
    float I0 = hx[hb + 2], I1 = hx[hb + 6], I2 = hx[hb + 10];
    float N0 = hx[hb + 3], N1 = hx[hb + 7], N2 = hx[hb + 11];

    const bool loS = (lane < 3);
    const float caL = loS ? npsL2 : namL2;
    const float cbL = loS ? psVR * L2E : 0.f;
    const float cdL = loS ? 1.f : 0.2f;
    const bool selB = (lane == 1) || (lane == 4);
    const bool selC = (lane == 2) || (lane == 5);
    const bool is63 = (lane == 63);

    float vE0s2 = cE0s2; PIN_V(vE0s2);
    float vN0s2 = cN0s2; PIN_V(vN0s2);
    float vE1e  = cE1e;  PIN_V(vE1e);
    float vE1s  = cE1s;  PIN_V(vE1s);
    float vE2e  = cE2e;  PIN_V(vE2e);
    float vE2s  = cE2s;  PIN_V(vE2s);
    float vI0   = cI0;   PIN_V(vI0);
    float vI1   = cI1;   PIN_V(vI1);
    float vN1   = cN1;   PIN_V(vN1);
    float vN2   = cN2;   PIN_V(vN2);
    float vngLVL = -gLVL; PIN_V(vngLVL);

    constexpr int NR = 8;
    float Wl[NR], Wf[NR], Wb[NR];
#pragma unroll
    for (int r = 0; r < NR; ++r) {
      int s = NR * lane + r;
      Wl[r] = Wall[wv][s];
      Wf[r] = Wall[wv][WSTR + s];
      Wb[r] = Wall[wv][2 * WSTR + s];
    }

    float Pl[NR], Pf[NR], Pb[NR], hbuf[NR];
#pragma unroll
    for (int r = 0; r < NR; ++r) { Pl[r] = 0.f; Pf[r] = 0.f; Pb[r] = 0.f; hbuf[r] = 0.f; }
    for (int d = 0; d <= maxd; ++d) {
      float wl_ = Wall[wv][d], wf_ = Wall[wv][WSTR + d], wb_ = Wall[wv][2 * WSTR + d];
#pragma unroll
      for (int r = NR - 1; r > 0; --r) hbuf[r] = hbuf[r - 1];
      int idx = d - NR * lane;
      bool ok = idx >= 0;
      float hv = hE_lds[wv][ok ? idx : 0];
      hbuf[0] = ok ? hv : 0.f;
#pragma unroll
      for (int r = 0; r < NR; ++r) {
        Pl[r] = fmaf(wl_, hbuf[r], Pl[r]);
        Pf[r] = fmaf(wf_, hbuf[r], Pf[r]);
        Pb[r] = fmaf(wb_, hbuf[r], Pb[r]);
      }
    }

    auto rotscat = [&](float* P, const float* W, float sPv) {
      float nl = is63 ? 0.f : wrol1(P[0]);
#pragma unroll
      for (int r = 0; r < NR - 1; ++r) P[r] = fmaf(W[r], sPv, P[r + 1]);
      P[NR - 1] = fmaf(W[NR - 1], sPv, nl);
    };

    for (int tr = 0; tr < TRS; ++tr) {
      float u_tr = (lane < STEPS) ? u_lds[wv][lane * TRS + tr] : 0.f;
#pragma unroll
      for (int st = 0; st < STEPS; ++st) {
        float t1 = bperm0_(Pl[0]);
        float t2 = bperm0_(Pf[0]);
        float t3 = bperm0_(Pb[0]);

        float Vs = selC ? V2 : (selB ? V1 : V0);
        float ex = __builtin_amdgcn_exp2f(fmaf(caL, Vs, cbL));
        float sg = rcp_(fmaf(cdL, ex, 1.f));
        float sE = rlane_(sg, 0), sI = rlane_(sg, 1), sP = rlane_(sg, 2);
        float m0 = rlane_(sg, 3), m1 = rlane_(sg, 4), m2 = rlane_(sg, 5);
        float U = rlane_(u_tr, st);

        float T0 = t1 + U;
        float T2 = t2 + U;
        float nE0 = fmaf(dk1, E0, fmaf(vE0s2, sP, T0));
        float nN0 = fmaf(dk1, N0, fmaf(vN0s2, sP, t1));
        float nE1 = fmaf(dk1, E1, fmaf(vE1e, sE, fmaf(vE1s, sP, t3)));
        float nN1 = fmaf(dk1, N1, vN1 * sE);
        float nE2 = fmaf(dk1, E2, fmaf(vE2e, sE, fmaf(vE2s, sP, T2)));
        float nN2 = fmaf(dk1, N2, vN2 * sE);
        float pI = vI0 * sI;
        float nI0 = fmaf(dk1, I0, pI);
        float nI1 = fmaf(dk1, I1, vI1 * sI);
        float nI2 = fmaf(dk1, I2, pI);

        float Nm0 = N0 * m0, Nm1 = N1 * m1, Nm2 = N2 * m2;
        float R0 = fmaf(E0, VE, fmaf(Nm0, VNMDA, fmaf(I0, -VI, vngLVL)));
        float R1 = fmaf(E1, VE, fmaf(Nm1, VNMDA, fmaf(I1, -VI, vngLVL)));
        float R2 = fmaf(E2, VE, fmaf(Nm2, VNMDA, fmaf(I2, -VI, vngLVL)));
        float S0 = gLp + E0 + I0 + Nm0;
        float S1 = gLp + E1 + I1 + Nm1;
        float S2 = gLp + E2 + I2 + Nm2;
        V0 = fmaf(DTC, fmaf(-S0, V0, R0), V0);
        V1 = fmaf(DTC, fmaf(-S1, V1, R1), V1);
        V2 = fmaf(DTC, fmaf(-S2, V2, R2), V2);
        E0 = nE0; E1 = nE1; E2 = nE2;
        I0 = nI0; I1 = nI1; I2 = nI2;
        N0 = nN0; N1 = nN1; N2 = nN2;

        rotscat(Pl, Wl, sP);
        rotscat(Pf, Wf, sP);
        rotscat(Pb, Wb, sP);
      }
      if (lane == 0) vsnap[tr * NODE + node] = V2;
    }
  }
}

// ---------------------------------------------------------------------------
// Kernel C: EEG readout. cm elimination: sum((lm-cm)@v) = a_o - mean_o(a_o).
// ---------------------------------------------------------------------------
__global__ __launch_bounds__(256) void eeg_kernel(
    const float* __restrict__ lm, const float* __restrict__ vsnap,
    const float* __restrict__ theta, float* __restrict__ out) {
  int tr = blockIdx.x;
  __shared__ float vs[NODE];
  __shared__ float partl[4][OUT];
  int tid = threadIdx.x;
  for (int n = tid; n < NODE; n += 256) vs[n] = vsnap[tr * NODE + n];
  __syncthreads();
  int o = tid & 63, w = tid >> 6;
  float acc = 0.f;
  for (int n = w * 100; n < w * 100 + 100; ++n)
    acc = fmaf(lm[o * NODE + n], vs[n], acc);
  partl[w][o] = acc;
  __syncthreads();
  if (tid < OUT) {
    float cy0 = theta[22], y0 = theta[19];
    float a = partl[0][tid] + partl[1][tid] + partl[2][tid] + partl[3][tid];
    float mean = wave_reduce1(a) * (1.f / OUT);
    out[tr * OUT + tid] = cy0 * (a - mean) - y0;
  }
}

extern "C" void kernel_launch(void* const* d_in, const int* in_sizes, int n_in,
                              void* d_out, int out_size, void* d_ws, size_t ws_size,
                              hipStream_t stream) {
  const float* external = (const float*)d_in[0];
  const float* hx       = (const float*)d_in[1];
  const float* hE       = (const float*)d_in[2];
  const float* sc       = (const float*)d_in[3];
  const float* dist     = (const float*)d_in[4];
  const float* wbb      = (const float*)d_in[5];
  const float* wff      = (const float*)d_in[6];
  const float* wll      = (const float*)d_in[7];
  const float* lm       = (const float*)d_in[8];
  const float* theta    = (const float*)d_in[9];
  float* out = (float*)d_out;

  float* vsnap = (float*)d_ws;               // TRS*NODE
  float* part  = vsnap + TRS * NODE;         // 3*64 ssq partials

  ssq_kernel<<<64, 256, 0, stream>>>(wbb, wff, wll, sc, part);
  sim_kernel<<<NODE / 2, 128, 0, stream>>>(external, hx, hE, sc, dist, wbb, wff,
                                           wll, theta, part, vsnap);
  eeg_kernel<<<TRS, 256, 0, stream>>>(lm, vsnap, theta, out);
}